// Round 10
// baseline (410.788 us; speedup 1.0000x reference)
//
#include <hip/hip_runtime.h>
#include <hip/hip_bf16.h>

#define IN_DIM 128
#define HID 256
#define BN_EPS 1e-5f

typedef __attribute__((ext_vector_type(8))) short bf16x8;
typedef __attribute__((ext_vector_type(16))) float f32x16;
typedef __attribute__((ext_vector_type(2))) float f32x2;

// ---------- helpers ----------
__device__ __forceinline__ float ld_f(const void* p, size_t i, int bf16) {
  if (bf16) return __bfloat162float(((const __hip_bfloat16*)p)[i]);
  return ((const float*)p)[i];
}
__device__ __forceinline__ float blo(unsigned u) { return __uint_as_float(u << 16); }
__device__ __forceinline__ float bhi(unsigned u) { return __uint_as_float(u & 0xffff0000u); }
__device__ __forceinline__ unsigned short f2bf(float f) {
  __hip_bfloat16 b = __float2bfloat16(f);
  return __builtin_bit_cast(unsigned short, b);
}
__device__ __forceinline__ void load_lds16(const void* g, void* l) {
  __builtin_amdgcn_global_load_lds((const __attribute__((address_space(1))) void*)g,
                                   (__attribute__((address_space(3))) void*)l, 16, 0, 0);
}
// order-preserving float->uint key (monotone increasing); init 0 is neutral for max
__device__ __forceinline__ unsigned fkey(float v) {
  unsigned s = __float_as_uint(v);
  return (s & 0x80000000u) ? ~s : (s | 0x80000000u);
}
__device__ __forceinline__ float finv(unsigned k) {
  unsigned s = (k & 0x80000000u) ? (k ^ 0x80000000u) : ~k;
  return __uint_as_float(s);
}

// ---------- mega prep: flag detect (per block) + histogram + x->A1 + W packs ----------
__global__ void prep_kernel(
    const void* __restrict__ x, const void* __restrict__ ei,
    const void* Wl_f1, const void* bl_f1, const void* Wr_f1,
    const void* Wl_b1, const void* bl_b1, const void* Wr_b1,
    const void* Wl_f2, const void* bl_f2, const void* Wr_f2,
    const void* Wl_b2, const void* bl_b2, const void* Wr_b2,
    const void* g1, const void* be1, const void* g2, const void* be2,
    int* __restrict__ degf, int* __restrict__ degb,
    __hip_bfloat16* __restrict__ A1,
    __hip_bfloat16* __restrict__ Wpk1, float* __restrict__ b1,
    __hip_bfloat16* __restrict__ Wpk2, float* __restrict__ b2,
    float* __restrict__ gamma1, float* __restrict__ beta1,
    float* __restrict__ gamma2, float* __restrict__ beta2,
    int n_nodes, int n_edges) {
  __shared__ int votes, nz;
  if (threadIdx.x == 0) { votes = 0; nz = 0; }
  __syncthreads();
  {
    unsigned e = (((const unsigned*)x)[threadIdx.x] >> 7) & 0xFFu;
    if (e >= 100u && e <= 140u) atomicAdd(&votes, 1);
    if (((const unsigned*)ei)[2 * threadIdx.x + 1] != 0u) atomicAdd(&nz, 1);
  }
  __syncthreads();
  const int bf = (votes > 128) ? 1 : 0;
  const int i32 = (nz > 0) ? 1 : 0;
  const int tid = blockIdx.x * 256 + threadIdx.x;
  const int nt = gridDim.x * 256;
  for (int i = tid; i < n_edges; i += nt) {
    int s, d;
    if (i32) { s = ((const int*)ei)[i]; d = ((const int*)ei)[n_edges + i]; }
    else     { s = (int)((const long long*)ei)[i]; d = (int)((const long long*)ei)[n_edges + i]; }
    atomicAdd(&degf[d], 1);
    atomicAdd(&degb[s], 1);
  }
  const size_t nq = (size_t)n_nodes * IN_DIM / 4;
  for (size_t q = tid; q < nq; q += nt) {
    const int row = (int)(q >> 5), j = (int)(q & 31) * 4;
    __hip_bfloat16* dstp = A1 + (size_t)row * 384 + 256 + j;
    if (bf) {
      *(uint2*)dstp = ((const uint2*)x)[q];
    } else {
      float4 v = ((const float4*)x)[q];
      unsigned short o[4] = {f2bf(v.x), f2bf(v.y), f2bf(v.z), f2bf(v.w)};
      *(uint2*)dstp = *(uint2*)o;
    }
  }
  for (int idx = tid; idx < 768 * 256; idx += nt) {
    {
      int j = idx & 7, l = (idx >> 3) & 63, rest = idx >> 9;
      int s = rest % 48, t = rest / 48;
      int k = s * 16 + (l >> 5) * 8 + j, col = t * 32 + (l & 31);
      float v;
      if (k < 256)      v = ld_f(Wl_f2, (size_t)k * 256 + col, bf);
      else if (k < 512) v = ld_f(Wl_b2, (size_t)(k - 256) * 256 + col, bf);
      else              v = ld_f(Wr_f2, (size_t)(k - 512) * 256 + col, bf) +
                            ld_f(Wr_b2, (size_t)(k - 512) * 256 + col, bf);
      Wpk2[idx] = __float2bfloat16(v);
    }
    if (idx < 384 * 256) {
      int j = idx & 7, l = (idx >> 3) & 63, rest = idx >> 9;
      int s = rest % 24, t = rest / 24;
      int k = s * 16 + (l >> 5) * 8 + j, col = t * 32 + (l & 31);
      float v;
      if (k < 128)      v = ld_f(Wl_f1, (size_t)k * 256 + col, bf);
      else if (k < 256) v = ld_f(Wl_b1, (size_t)(k - 128) * 256 + col, bf);
      else              v = ld_f(Wr_f1, (size_t)(k - 256) * 256 + col, bf) +
                            ld_f(Wr_b1, (size_t)(k - 256) * 256 + col, bf);
      Wpk1[idx] = __float2bfloat16(v);
    }
    if (idx < 256) {
      b1[idx] = ld_f(bl_f1, idx, bf) + ld_f(bl_b1, idx, bf);
      b2[idx] = ld_f(bl_f2, idx, bf) + ld_f(bl_b2, idx, bf);
      gamma1[idx] = ld_f(g1, idx, bf);
      beta1[idx]  = ld_f(be1, idx, bf);
      gamma2[idx] = ld_f(g2, idx, bf);
      beta2[idx]  = ld_f(be2, idx, bf);
    }
  }
}

// ---------- CSR build ----------
__global__ void scan_part_kernel(const int* __restrict__ degf, const int* __restrict__ degb,
                                 int* __restrict__ offf, int* __restrict__ offb,
                                 int* __restrict__ partials, int n, int nb) {
  __shared__ int buf[256];
  const int b = blockIdx.x;
  const int* deg = (b < nb) ? degf : degb;
  int* off = (b < nb) ? offf : offb;
  const int chunk = (b < nb) ? b : (b - nb);
  const int i = chunk * 256 + threadIdx.x;
  int v = (i < n) ? deg[i] : 0;
  buf[threadIdx.x] = v;
  __syncthreads();
  for (int s = 1; s < 256; s <<= 1) {
    int t = (threadIdx.x >= s) ? buf[threadIdx.x - s] : 0;
    __syncthreads();
    buf[threadIdx.x] += t;
    __syncthreads();
  }
  if (i < n) off[i] = buf[threadIdx.x] - v;
  if (threadIdx.x == 255) partials[b] = buf[255];
}

// merged: each block reduces its own prefix over partials (nb <= 256) then adds
__global__ void scan_add_kernel(int* __restrict__ offf, int* __restrict__ offb,
                                int* __restrict__ curf, int* __restrict__ curb,
                                const int* __restrict__ partials, int n, int nb, int n_edges) {
  __shared__ int red[256];
  const int b = blockIdx.x;
  int* off = (b < nb) ? offf : offb;
  int* cur = (b < nb) ? curf : curb;
  const int chunk = (b < nb) ? b : (b - nb);
  const int abase = (b < nb) ? 0 : nb;
  int v = (threadIdx.x < chunk) ? partials[abase + threadIdx.x] : 0;
  red[threadIdx.x] = v;
  __syncthreads();
  for (int s = 128; s > 0; s >>= 1) {
    if (threadIdx.x < s) red[threadIdx.x] += red[threadIdx.x + s];
    __syncthreads();
  }
  const int prefix = red[0];
  const int i = chunk * 256 + threadIdx.x;
  if (i < n) {
    int t = off[i] + prefix;
    off[i] = t;
    cur[i] = t;
  }
  if (b == 0 && threadIdx.x == 0) { offf[n] = n_edges; offb[n] = n_edges; }
}

// decodes edge_index directly (per-block int64 vote)
__global__ void fill_adj_kernel(const void* __restrict__ ei,
                                int* __restrict__ curf, int* __restrict__ curb,
                                int* __restrict__ adjf, int* __restrict__ adjb, int n_edges) {
  __shared__ int nz;
  if (threadIdx.x == 0) nz = 0;
  __syncthreads();
  if (((const unsigned*)ei)[2 * threadIdx.x + 1] != 0u) atomicAdd(&nz, 1);
  __syncthreads();
  const int i32 = nz > 0;
  int i = blockIdx.x * 256 + threadIdx.x;
  if (i >= n_edges) return;
  int s, d;
  if (i32) { s = ((const int*)ei)[i]; d = ((const int*)ei)[n_edges + i]; }
  else     { s = (int)((const long long*)ei)[i]; d = (int)((const long long*)ei)[n_edges + i]; }
  adjf[atomicAdd(&curf[d], 1)] = s;
  adjb[atomicAdd(&curb[s], 1)] = d;
}

// ---------- gather-mean v4: f32x2 pk-add accumulate, 32-bit offsets, 6 rows in flight ----------
template <int D>
__global__ __launch_bounds__(256) void gather_mean_kernel(
    __hip_bfloat16* __restrict__ A,
    const int* __restrict__ adjf, const int* __restrict__ offf,
    const int* __restrict__ adjb, const int* __restrict__ offb, int n_nodes) {
  constexpr int LPN = D / 8;
  constexpr int NPI = 64 / LPN;
  constexpr unsigned RSTRIDE = 3 * D * 2;  // row stride in bytes (fits 32-bit total)
  const int gw = (int)(((size_t)blockIdx.x * 256 + threadIdx.x) >> 6);
  const int lane = threadIdx.x & 63;
  if (gw >= 2 * n_nodes) return;
  int node, dir;
  const int *adj, *off;
  if (gw < n_nodes) { node = gw;           adj = adjf; off = offf; dir = 0; }
  else              { node = gw - n_nodes; adj = adjb; off = offb; dir = 1; }
  const int s = off[node], e = off[node + 1];
  const int sub = lane / LPN, cl = lane % LPN;
  const char* Abase = (const char*)A + 4 * (size_t)D + cl * 16;  // self-slice col offset
  auto clampi = [&](int i) { return max(min(i, e - 1), 0); };
  auto ROW = [&](int a) {
    return *(const uint4*)(Abase + (size_t)((unsigned)a * RSTRIDE));
  };
  f32x2 acc0 = {0.f, 0.f}, acc1 = acc0, acc2 = acc0, acc3 = acc0;
#define ACC(r) { f32x2 t;                                  \
    t[0] = blo(r.x); t[1] = bhi(r.x); acc0 += t;           \
    t[0] = blo(r.y); t[1] = bhi(r.y); acc1 += t;           \
    t[0] = blo(r.z); t[1] = bhi(r.z); acc2 += t;           \
    t[0] = blo(r.w); t[1] = bhi(r.w); acc3 += t; }
  int i = s + sub;
  int a0 = adj[clampi(i)];
  int a1 = adj[clampi(i + NPI)];
  int a2 = adj[clampi(i + 2 * NPI)];
  int a3 = adj[clampi(i + 3 * NPI)];
  uint4 r0 = ROW(a0), r1 = ROW(a1), r2 = ROW(a2), r3 = ROW(a3);
  int a4 = adj[clampi(i + 4 * NPI)];
  int a5 = adj[clampi(i + 5 * NPI)];
  for (; i < e; i += 2 * NPI) {
    const uint4 n0 = ROW(a4), n1 = ROW(a5);
    const int b0 = adj[clampi(i + 6 * NPI)];
    const int b1 = adj[clampi(i + 7 * NPI)];
    ACC(r0);
    if (i + NPI < e) ACC(r1);
    r0 = r2; r1 = r3; r2 = n0; r3 = n1;
    a4 = b0; a5 = b1;
  }
#undef ACC
  float accs[8] = {acc0[0], acc0[1], acc1[0], acc1[1], acc2[0], acc2[1], acc3[0], acc3[1]};
#pragma unroll
  for (int o = 32; o >= LPN; o >>= 1) {
#pragma unroll
    for (int k = 0; k < 8; ++k) accs[k] += __shfl_xor(accs[k], o, 64);
  }
  if (sub == 0) {
    const float inv = 1.0f / (float)max(e - s, 1);
    union { unsigned short us[8]; uint4 v; } o;
#pragma unroll
    for (int k = 0; k < 8; ++k) o.us[k] = f2bf(accs[k] * inv);
    *(uint4*)(A + (size_t)node * (3 * D) + dir * D + cl * 8) = o.v;
  }
}

// ---------- MFMA GEMM: 128x256/block, BK=128 double-buffered LDS, fused stats ----------
// STORE=true  (layer 1): writes bf16 pre-BN into Cb (stride 768, col off 512); sums only.
// STORE=false (layer 2): no C store; sums + order-key max/min; LAST BLOCK runs finalize.
template <int K, bool STORE>
__global__ __launch_bounds__(256, 2) void gemm_mfma_kernel(
    const __hip_bfloat16* __restrict__ A, const __hip_bfloat16* __restrict__ Wpk,
    const float* __restrict__ bias, __hip_bfloat16* __restrict__ Cb,
    float* __restrict__ bnsum, float* __restrict__ bnsum2,
    unsigned* __restrict__ gmax, unsigned* __restrict__ gmin,
    int* __restrict__ counter, const unsigned* __restrict__ xw,
    const float* __restrict__ gamma, const float* __restrict__ beta,
    float inv_n, void* __restrict__ out, int out_size, int M) {
  constexpr int S = K / 16;
  constexpr int NIT = K / 128;
  __shared__ __align__(16) char Atile[2][32768];
  __shared__ float colsum[256], colsum2[256];
  __shared__ unsigned cmax[256], cmin[256];
  __shared__ int lastflag, votes;
  colsum[threadIdx.x] = 0.f; colsum2[threadIdx.x] = 0.f;
  if (!STORE) { cmax[threadIdx.x] = 0u; cmin[threadIdx.x] = 0u; }
  const int wave = threadIdx.x >> 6, lane = threadIdx.x & 63;
  const int rw = wave >> 1, cw = wave & 1;
  const int rbase = blockIdx.x * 128;
  const __hip_bfloat16* gsrc = A + (size_t)(rbase + wave * 32 + (lane >> 1)) * K + (lane & 1) * 8;
  char* lb[2] = { &Atile[0][wave * 1024], &Atile[1][wave * 1024] };

  {
    const __hip_bfloat16* g = gsrc;
#pragma unroll
    for (int d = 0; d < 8; ++d) load_lds16(g + d * 16, lb[0] + d * 4096);
  }

  const __hip_bfloat16* wbase = Wpk + ((size_t)(cw * 4) * S * 64 + lane) * 8;
  const int aoff = (lane & 31) * 32 + (lane >> 5) * 16;
  f32x16 acc[2][4] = {};

  for (int kb = 0; kb < NIT; ++kb) {
    __syncthreads();
    if (kb + 1 < NIT) {
      const __hip_bfloat16* g = gsrc + (size_t)(kb + 1) * 128;
      char* l = lb[(kb + 1) & 1];
#pragma unroll
      for (int d = 0; d < 8; ++d) load_lds16(g + d * 16, l + d * 4096);
    }
    const char* ab = Atile[kb & 1];
#pragma unroll
    for (int s = 0; s < 8; ++s) {
      const int ks = kb * 8 + s;
      const bf16x8 a0 = *(const bf16x8*)(ab + (s * 4 + rw * 2 + 0) * 1024 + aoff);
      const bf16x8 a1 = *(const bf16x8*)(ab + (s * 4 + rw * 2 + 1) * 1024 + aoff);
      const bf16x8 w0 = *(const bf16x8*)(wbase + ((size_t)0 * S + ks) * 512);
      const bf16x8 w1 = *(const bf16x8*)(wbase + ((size_t)1 * S + ks) * 512);
      const bf16x8 w2 = *(const bf16x8*)(wbase + ((size_t)2 * S + ks) * 512);
      const bf16x8 w3 = *(const bf16x8*)(wbase + ((size_t)3 * S + ks) * 512);
      acc[0][0] = __builtin_amdgcn_mfma_f32_32x32x16_bf16(a0, w0, acc[0][0], 0, 0, 0);
      acc[0][1] = __builtin_amdgcn_mfma_f32_32x32x16_bf16(a0, w1, acc[0][1], 0, 0, 0);
      acc[0][2] = __builtin_amdgcn_mfma_f32_32x32x16_bf16(a0, w2, acc[0][2], 0, 0, 0);
      acc[0][3] = __builtin_amdgcn_mfma_f32_32x32x16_bf16(a0, w3, acc[0][3], 0, 0, 0);
      acc[1][0] = __builtin_amdgcn_mfma_f32_32x32x16_bf16(a1, w0, acc[1][0], 0, 0, 0);
      acc[1][1] = __builtin_amdgcn_mfma_f32_32x32x16_bf16(a1, w1, acc[1][1], 0, 0, 0);
      acc[1][2] = __builtin_amdgcn_mfma_f32_32x32x16_bf16(a1, w2, acc[1][2], 0, 0, 0);
      acc[1][3] = __builtin_amdgcn_mfma_f32_32x32x16_bf16(a1, w3, acc[1][3], 0, 0, 0);
    }
  }

#pragma unroll
  for (int rh = 0; rh < 2; ++rh) {
#pragma unroll
    for (int t = 0; t < 4; ++t) {
      const int col = cw * 128 + t * 32 + (lane & 31);
      const float bj = bias[col];
      float ls = 0.f, ls2 = 0.f, lmax = -INFINITY, lmin = INFINITY;
#pragma unroll
      for (int r = 0; r < 16; ++r) {
        const int row = rbase + rw * 64 + rh * 32 + (r & 3) + 8 * (r >> 2) + 4 * (lane >> 5);
        if (row < M) {
          float v = acc[rh][t][r] + bj;
          if (STORE) Cb[(size_t)row * 768 + 512 + col] = __float2bfloat16(v);
          ls += v;
          ls2 = fmaf(v, v, ls2);
          if (!STORE) { lmax = fmaxf(lmax, v); lmin = fminf(lmin, v); }
        }
      }
      atomicAdd(&colsum[col], ls);
      atomicAdd(&colsum2[col], ls2);
      if (!STORE) {
        atomicMax(&cmax[col], fkey(lmax));
        atomicMax(&cmin[col], ~fkey(lmin));
      }
    }
  }
  __syncthreads();
  atomicAdd(&bnsum[threadIdx.x], colsum[threadIdx.x]);
  atomicAdd(&bnsum2[threadIdx.x], colsum2[threadIdx.x]);
  if (!STORE) {
    atomicMax(&gmax[threadIdx.x], cmax[threadIdx.x]);
    atomicMax(&gmin[threadIdx.x], cmin[threadIdx.x]);
    __threadfence();
    if (threadIdx.x == 0) {
      lastflag = (atomicAdd(counter, 1) == (int)gridDim.x - 1);
      votes = 0;
    }
    __syncthreads();
    if (lastflag) {
      unsigned e = (xw[threadIdx.x] >> 7) & 0xFFu;
      if (e >= 100u && e <= 140u) atomicAdd(&votes, 1);
      __syncthreads();
      const int bf = votes > 128;
      const int j = threadIdx.x;
      if (j < out_size) {
        // atomic reads: guaranteed coherent view of all blocks' updates
        float sv = atomicAdd(&bnsum[j], 0.f);
        float s2 = atomicAdd(&bnsum2[j], 0.f);
        unsigned km = atomicAdd(&gmax[j], 0u);
        unsigned kn = atomicAdd(&gmin[j], 0u);
        float mu = sv * inv_n;
        float rs = rsqrtf(fmaxf(s2 * inv_n - mu * mu, 0.f) + BN_EPS);
        float g = gamma[j] * rs, b = fmaf(-mu, g, beta[j]);
        float vmax = finv(km), vmin = finv(~kn);
        float v = fmaxf(fmaf(g, (g >= 0.f) ? vmax : vmin, b), 0.f);
        if (bf) ((__hip_bfloat16*)out)[j] = __float2bfloat16(v);
        else    ((float*)out)[j] = v;
      }
    }
  }
}

// ---------- BN+ReLU in place on A2 self-slice (4 cols/thread, 4 rows/block) ----------
__global__ void bn_apply_kernel(__hip_bfloat16* __restrict__ A2,
                                const float* __restrict__ sum, const float* __restrict__ sumsq,
                                const float* __restrict__ gamma, const float* __restrict__ beta,
                                int n_nodes, float inv_n) {
  const int j0 = (threadIdx.x & 63) * 4;
  const int row = blockIdx.x * 4 + (threadIdx.x >> 6);
  if (row >= n_nodes) return;
  float g[4], b[4];
#pragma unroll
  for (int k = 0; k < 4; ++k) {
    const int j = j0 + k;
    float mu = sum[j] * inv_n;
    float rs = rsqrtf(fmaxf(sumsq[j] * inv_n - mu * mu, 0.f) + BN_EPS);
    g[k] = gamma[j] * rs;
    b[k] = fmaf(-mu, g[k], beta[j]);
  }
  uint2* p = (uint2*)(A2 + (size_t)row * 768 + 512 + j0);
  uint2 w = *p;
  unsigned short us[4];
  us[0] = f2bf(fmaxf(fmaf(blo(w.x), g[0], b[0]), 0.f));
  us[1] = f2bf(fmaxf(fmaf(bhi(w.x), g[1], b[1]), 0.f));
  us[2] = f2bf(fmaxf(fmaf(blo(w.y), g[2], b[2]), 0.f));
  us[3] = f2bf(fmaxf(fmaf(bhi(w.y), g[3], b[3]), 0.f));
  *p = *(uint2*)us;
}

extern "C" void kernel_launch(void* const* d_in, const int* in_sizes, int n_in,
                              void* d_out, int out_size, void* d_ws, size_t ws_size,
                              hipStream_t stream) {
  const void* x  = d_in[0];
  const void* ei = d_in[1];
  const int n_nodes = in_sizes[0] / IN_DIM;
  const int n_edges = in_sizes[1] / 2;
  const int nb = (n_nodes + 255) / 256;
  const int Mpad = (n_nodes + 127) & ~127;

  float* ws = (float*)d_ws;
  size_t off = 0;
  auto alloc = [&](size_t n) {
    float* p = ws + off;
    off += (n + 1023) & ~(size_t)1023;
    return p;
  };
  __hip_bfloat16* Wpk1 = (__hip_bfloat16*)alloc(384 * 256 / 2);
  __hip_bfloat16* Wpk2 = (__hip_bfloat16*)alloc(768 * 256 / 2);
  float* b1      = alloc(256);
  float* b2      = alloc(256);
  float* gamma1  = alloc(256);
  float* beta1   = alloc(256);
  float* gamma2  = alloc(256);
  float* beta2   = alloc(256);
  float* zeros   = alloc(2 * (size_t)n_nodes + 2048);
  int*   degf    = (int*)zeros;
  int*   degb    = degf + n_nodes;
  float* sum1    = zeros + 2 * (size_t)n_nodes;
  float* sumsq1  = sum1 + 256;
  float* sum2    = sum1 + 512;
  float* sumsq2  = sum1 + 768;
  unsigned* max2 = (unsigned*)(sum1 + 1024);
  unsigned* min2 = (unsigned*)(sum1 + 1280);
  int*   counter = (int*)(sum1 + 1536);
  int*   offf    = (int*)alloc(n_nodes + 1);
  int*   offb    = (int*)alloc(n_nodes + 1);
  int*   curf    = (int*)alloc(n_nodes);
  int*   curb    = (int*)alloc(n_nodes);
  int*   adjf    = (int*)alloc(n_edges);
  int*   adjb    = (int*)alloc(n_edges);
  int*   partials = (int*)alloc(2 * nb);
  __hip_bfloat16* A1 = (__hip_bfloat16*)alloc((size_t)Mpad * 384 / 2);
  __hip_bfloat16* A2 = (__hip_bfloat16*)alloc((size_t)Mpad * 768 / 2);
  (void)ws_size; (void)n_in;

  hipMemsetAsync(zeros, 0, (2 * (size_t)n_nodes + 2048) * 4, stream);

  const int pgrid = (n_edges + 255) / 256;
  prep_kernel<<<pgrid, 256, 0, stream>>>(
      x, ei,
      d_in[2], d_in[3], d_in[4], d_in[5], d_in[6], d_in[7],
      d_in[8], d_in[9], d_in[10], d_in[11], d_in[12], d_in[13],
      d_in[14], d_in[15], d_in[16], d_in[17],
      degf, degb, A1,
      Wpk1, b1, Wpk2, b2, gamma1, beta1, gamma2, beta2, n_nodes, n_edges);

  scan_part_kernel<<<2 * nb, 256, 0, stream>>>(degf, degb, offf, offb, partials, n_nodes, nb);
  scan_add_kernel<<<2 * nb, 256, 0, stream>>>(offf, offb, curf, curb, partials, n_nodes, nb, n_edges);
  fill_adj_kernel<<<(n_edges + 255) / 256, 256, 0, stream>>>(ei, curf, curb, adjf, adjb, n_edges);

  const float inv_n = 1.0f / (float)n_nodes;
  const int gemm_grid = Mpad / 128;

  // ---- layer 1 ----
  gather_mean_kernel<IN_DIM><<<(2 * n_nodes + 3) / 4, 256, 0, stream>>>(
      A1, adjf, offf, adjb, offb, n_nodes);
  gemm_mfma_kernel<384, true><<<gemm_grid, 256, 0, stream>>>(
      A1, Wpk1, b1, A2, sum1, sumsq1, max2, min2, counter, (const unsigned*)x,
      gamma1, beta1, inv_n, d_out, out_size, n_nodes);
  bn_apply_kernel<<<(n_nodes + 3) / 4, 256, 0, stream>>>(
      A2, sum1, sumsq1, gamma1, beta1, n_nodes, inv_n);

  // ---- layer 2 (no C store; stats+max/min fused; last block writes output) ----
  gather_mean_kernel<HID><<<(2 * n_nodes + 3) / 4, 256, 0, stream>>>(
      A2, adjf, offf, adjb, offb, n_nodes);
  gemm_mfma_kernel<768, false><<<gemm_grid, 256, 0, stream>>>(
      A2, Wpk2, b2, nullptr, sum2, sumsq2, max2, min2, counter, (const unsigned*)x,
      gamma2, beta2, inv_n, d_out, out_size, n_nodes);
}

// Round 11
// 395.164 us; speedup vs baseline: 1.0395x; 1.0395x over previous
//
#include <hip/hip_runtime.h>
#include <hip/hip_bf16.h>

#define IN_DIM 128
#define HID 256
#define BN_EPS 1e-5f

typedef __attribute__((ext_vector_type(8))) short bf16x8;
typedef __attribute__((ext_vector_type(16))) float f32x16;

// ---------- helpers ----------
__device__ __forceinline__ float ld_f(const void* p, size_t i, int bf16) {
  if (bf16) return __bfloat162float(((const __hip_bfloat16*)p)[i]);
  return ((const float*)p)[i];
}
__device__ __forceinline__ float blo(unsigned u) { return __uint_as_float(u << 16); }
__device__ __forceinline__ float bhi(unsigned u) { return __uint_as_float(u & 0xffff0000u); }
__device__ __forceinline__ unsigned short f2bf(float f) {
  __hip_bfloat16 b = __float2bfloat16(f);
  return __builtin_bit_cast(unsigned short, b);
}
__device__ __forceinline__ void load_lds16(const void* g, void* l) {
  __builtin_amdgcn_global_load_lds((const __attribute__((address_space(1))) void*)g,
                                   (__attribute__((address_space(3))) void*)l, 16, 0, 0);
}
// order-preserving float->uint key (monotone increasing); init 0 is neutral for max
__device__ __forceinline__ unsigned fkey(float v) {
  unsigned s = __float_as_uint(v);
  return (s & 0x80000000u) ? ~s : (s | 0x80000000u);
}
__device__ __forceinline__ float finv(unsigned k) {
  unsigned s = (k & 0x80000000u) ? (k ^ 0x80000000u) : ~k;
  return __uint_as_float(s);
}

// ---------- mega prep: flag detect (per block) + histogram + x->A1 + W packs ----------
__global__ void prep_kernel(
    const void* __restrict__ x, const void* __restrict__ ei,
    const void* Wl_f1, const void* bl_f1, const void* Wr_f1,
    const void* Wl_b1, const void* bl_b1, const void* Wr_b1,
    const void* Wl_f2, const void* bl_f2, const void* Wr_f2,
    const void* Wl_b2, const void* bl_b2, const void* Wr_b2,
    const void* g1, const void* be1, const void* g2, const void* be2,
    int* __restrict__ degf, int* __restrict__ degb,
    __hip_bfloat16* __restrict__ A1,
    __hip_bfloat16* __restrict__ Wpk1, float* __restrict__ b1,
    __hip_bfloat16* __restrict__ Wpk2, float* __restrict__ b2,
    float* __restrict__ gamma1, float* __restrict__ beta1,
    float* __restrict__ gamma2, float* __restrict__ beta2,
    int n_nodes, int n_edges) {
  __shared__ int votes, nz;
  if (threadIdx.x == 0) { votes = 0; nz = 0; }
  __syncthreads();
  {
    unsigned e = (((const unsigned*)x)[threadIdx.x] >> 7) & 0xFFu;
    if (e >= 100u && e <= 140u) atomicAdd(&votes, 1);
    if (((const unsigned*)ei)[2 * threadIdx.x + 1] != 0u) atomicAdd(&nz, 1);
  }
  __syncthreads();
  const int bf = (votes > 128) ? 1 : 0;
  const int i32 = (nz > 0) ? 1 : 0;
  const int tid = blockIdx.x * 256 + threadIdx.x;
  const int nt = gridDim.x * 256;
  for (int i = tid; i < n_edges; i += nt) {
    int s, d;
    if (i32) { s = ((const int*)ei)[i]; d = ((const int*)ei)[n_edges + i]; }
    else     { s = (int)((const long long*)ei)[i]; d = (int)((const long long*)ei)[n_edges + i]; }
    atomicAdd(&degf[d], 1);
    atomicAdd(&degb[s], 1);
  }
  const size_t nq = (size_t)n_nodes * IN_DIM / 4;
  for (size_t q = tid; q < nq; q += nt) {
    const int row = (int)(q >> 5), j = (int)(q & 31) * 4;
    __hip_bfloat16* dstp = A1 + (size_t)row * 384 + 256 + j;
    if (bf) {
      *(uint2*)dstp = ((const uint2*)x)[q];
    } else {
      float4 v = ((const float4*)x)[q];
      unsigned short o[4] = {f2bf(v.x), f2bf(v.y), f2bf(v.z), f2bf(v.w)};
      *(uint2*)dstp = *(uint2*)o;
    }
  }
  for (int idx = tid; idx < 768 * 256; idx += nt) {
    {
      int j = idx & 7, l = (idx >> 3) & 63, rest = idx >> 9;
      int s = rest % 48, t = rest / 48;
      int k = s * 16 + (l >> 5) * 8 + j, col = t * 32 + (l & 31);
      float v;
      if (k < 256)      v = ld_f(Wl_f2, (size_t)k * 256 + col, bf);
      else if (k < 512) v = ld_f(Wl_b2, (size_t)(k - 256) * 256 + col, bf);
      else              v = ld_f(Wr_f2, (size_t)(k - 512) * 256 + col, bf) +
                            ld_f(Wr_b2, (size_t)(k - 512) * 256 + col, bf);
      Wpk2[idx] = __float2bfloat16(v);
    }
    if (idx < 384 * 256) {
      int j = idx & 7, l = (idx >> 3) & 63, rest = idx >> 9;
      int s = rest % 24, t = rest / 24;
      int k = s * 16 + (l >> 5) * 8 + j, col = t * 32 + (l & 31);
      float v;
      if (k < 128)      v = ld_f(Wl_f1, (size_t)k * 256 + col, bf);
      else if (k < 256) v = ld_f(Wl_b1, (size_t)(k - 128) * 256 + col, bf);
      else              v = ld_f(Wr_f1, (size_t)(k - 256) * 256 + col, bf) +
                            ld_f(Wr_b1, (size_t)(k - 256) * 256 + col, bf);
      Wpk1[idx] = __float2bfloat16(v);
    }
    if (idx < 256) {
      b1[idx] = ld_f(bl_f1, idx, bf) + ld_f(bl_b1, idx, bf);
      b2[idx] = ld_f(bl_f2, idx, bf) + ld_f(bl_b2, idx, bf);
      gamma1[idx] = ld_f(g1, idx, bf);
      beta1[idx]  = ld_f(be1, idx, bf);
      gamma2[idx] = ld_f(g2, idx, bf);
      beta2[idx]  = ld_f(be2, idx, bf);
    }
  }
}

// ---------- CSR build ----------
__global__ void scan_part_kernel(const int* __restrict__ degf, const int* __restrict__ degb,
                                 int* __restrict__ offf, int* __restrict__ offb,
                                 int* __restrict__ partials, int n, int nb) {
  __shared__ int buf[256];
  const int b = blockIdx.x;
  const int* deg = (b < nb) ? degf : degb;
  int* off = (b < nb) ? offf : offb;
  const int chunk = (b < nb) ? b : (b - nb);
  const int i = chunk * 256 + threadIdx.x;
  int v = (i < n) ? deg[i] : 0;
  buf[threadIdx.x] = v;
  __syncthreads();
  for (int s = 1; s < 256; s <<= 1) {
    int t = (threadIdx.x >= s) ? buf[threadIdx.x - s] : 0;
    __syncthreads();
    buf[threadIdx.x] += t;
    __syncthreads();
  }
  if (i < n) off[i] = buf[threadIdx.x] - v;
  if (threadIdx.x == 255) partials[b] = buf[255];
}

// merged: each block reduces its own prefix over partials (nb <= 256) then adds
__global__ void scan_add_kernel(int* __restrict__ offf, int* __restrict__ offb,
                                int* __restrict__ curf, int* __restrict__ curb,
                                const int* __restrict__ partials, int n, int nb, int n_edges) {
  __shared__ int red[256];
  const int b = blockIdx.x;
  int* off = (b < nb) ? offf : offb;
  int* cur = (b < nb) ? curf : curb;
  const int chunk = (b < nb) ? b : (b - nb);
  const int abase = (b < nb) ? 0 : nb;
  int v = (threadIdx.x < chunk) ? partials[abase + threadIdx.x] : 0;
  red[threadIdx.x] = v;
  __syncthreads();
  for (int s = 128; s > 0; s >>= 1) {
    if (threadIdx.x < s) red[threadIdx.x] += red[threadIdx.x + s];
    __syncthreads();
  }
  const int prefix = red[0];
  const int i = chunk * 256 + threadIdx.x;
  if (i < n) {
    int t = off[i] + prefix;
    off[i] = t;
    cur[i] = t;
  }
  if (b == 0 && threadIdx.x == 0) { offf[n] = n_edges; offb[n] = n_edges; }
}

// decodes edge_index directly (per-block int64 vote)
__global__ void fill_adj_kernel(const void* __restrict__ ei,
                                int* __restrict__ curf, int* __restrict__ curb,
                                int* __restrict__ adjf, int* __restrict__ adjb, int n_edges) {
  __shared__ int nz;
  if (threadIdx.x == 0) nz = 0;
  __syncthreads();
  if (((const unsigned*)ei)[2 * threadIdx.x + 1] != 0u) atomicAdd(&nz, 1);
  __syncthreads();
  const int i32 = nz > 0;
  int i = blockIdx.x * 256 + threadIdx.x;
  if (i >= n_edges) return;
  int s, d;
  if (i32) { s = ((const int*)ei)[i]; d = ((const int*)ei)[n_edges + i]; }
  else     { s = (int)((const long long*)ei)[i]; d = (int)((const long long*)ei)[n_edges + i]; }
  adjf[atomicAdd(&curf[d], 1)] = s;
  adjb[atomicAdd(&curb[s], 1)] = d;
}

// ---------- gather-mean v3 (benched 58.6us): unroll x2, 4 rows + 2 idx in flight ----------
template <int D>
__global__ __launch_bounds__(256) void gather_mean_kernel(
    __hip_bfloat16* __restrict__ A,
    const int* __restrict__ adjf, const int* __restrict__ offf,
    const int* __restrict__ adjb, const int* __restrict__ offb, int n_nodes) {
  constexpr int LPN = D / 8;
  constexpr int NPI = 64 / LPN;
  const int gw = (int)(((size_t)blockIdx.x * 256 + threadIdx.x) >> 6);
  const int lane = threadIdx.x & 63;
  if (gw >= 2 * n_nodes) return;
  int node, dir;
  const int *adj, *off;
  if (gw < n_nodes) { node = gw;           adj = adjf; off = offf; dir = 0; }
  else              { node = gw - n_nodes; adj = adjb; off = offb; dir = 1; }
  const int s = off[node], e = off[node + 1];
  const int sub = lane / LPN, cl = lane % LPN;
  const size_t coloff = 2 * (size_t)D + cl * 8;
  auto clampi = [&](int i) { return max(min(i, e - 1), 0); };
  auto ROW = [&](int a) { return *(const uint4*)(A + (size_t)a * (3 * D) + coloff); };
  float acc[8] = {0.f, 0.f, 0.f, 0.f, 0.f, 0.f, 0.f, 0.f};
  int i = s + sub;
  int a0 = adj[clampi(i)];
  int a1 = adj[clampi(i + NPI)];
  int a2 = adj[clampi(i + 2 * NPI)];
  int a3 = adj[clampi(i + 3 * NPI)];
  uint4 r0 = ROW(a0);
  uint4 r1 = ROW(a1);
  for (; i < e; i += 2 * NPI) {
    const uint4 r2 = ROW(a2), r3 = ROW(a3);  // next pair in flight
    const int a4 = adj[clampi(i + 4 * NPI)];
    const int a5 = adj[clampi(i + 5 * NPI)];
    acc[0] += blo(r0.x); acc[1] += bhi(r0.x);
    acc[2] += blo(r0.y); acc[3] += bhi(r0.y);
    acc[4] += blo(r0.z); acc[5] += bhi(r0.z);
    acc[6] += blo(r0.w); acc[7] += bhi(r0.w);
    if (i + NPI < e) {
      acc[0] += blo(r1.x); acc[1] += bhi(r1.x);
      acc[2] += blo(r1.y); acc[3] += bhi(r1.y);
      acc[4] += blo(r1.z); acc[5] += bhi(r1.z);
      acc[6] += blo(r1.w); acc[7] += bhi(r1.w);
    }
    r0 = r2; r1 = r3; a2 = a4; a3 = a5;
  }
#pragma unroll
  for (int o = 32; o >= LPN; o >>= 1) {
#pragma unroll
    for (int k = 0; k < 8; ++k) acc[k] += __shfl_xor(acc[k], o, 64);
  }
  if (sub == 0) {
    const float inv = 1.0f / (float)max(e - s, 1);
    union { unsigned short us[8]; uint4 v; } o;
#pragma unroll
    for (int k = 0; k < 8; ++k) o.us[k] = f2bf(acc[k] * inv);
    *(uint4*)(A + (size_t)node * (3 * D) + dir * D + cl * 8) = o.v;
  }
}

// ---------- MFMA GEMM v7: 128x256/block, BK=64 double-buffered LDS (36KB total) ----------
// 4 waves, each 64r x 128c (8 C-frags / 128 AGPRs). Grid 391 fits 2 blocks/CU in ONE pass.
// Conflict-free LDS: DMA lane i stages row (i&31), k-half (i>>5) -> reader lane l reads at
// exactly l*16 within its 1KB microtile (wave-contiguous, zero bank conflicts).
// Microtile (s, rg) = 32 rows x 16 cols at offset (s*4+rg)*1024; s=k-step 0..3 within BK.
// STORE=true (layer 1): writes bf16 pre-BN to Cb (stride 768, off 512); sums only.
// STORE=false (layer 2): no C store; sums + order-key max/min; LAST BLOCK runs finalize.
template <int K, bool STORE>
__global__ __launch_bounds__(256, 2) void gemm_mfma_kernel(
    const __hip_bfloat16* __restrict__ A, const __hip_bfloat16* __restrict__ Wpk,
    const float* __restrict__ bias, __hip_bfloat16* __restrict__ Cb,
    float* __restrict__ bnsum, float* __restrict__ bnsum2,
    unsigned* __restrict__ gmax, unsigned* __restrict__ gmin,
    int* __restrict__ counter, const unsigned* __restrict__ xw,
    const float* __restrict__ gamma, const float* __restrict__ beta,
    float inv_n, void* __restrict__ out, int out_size, int M) {
  constexpr int S = K / 16;    // total k-steps
  constexpr int NIT = K / 64;  // BK=64 iterations
  __shared__ __align__(16) char Atile[2][16384];
  __shared__ float colsum[256], colsum2[256];
  __shared__ unsigned cmax[256], cmin[256];
  __shared__ int lastflag, votes;
  colsum[threadIdx.x] = 0.f; colsum2[threadIdx.x] = 0.f;
  if (!STORE) { cmax[threadIdx.x] = 0u; cmin[threadIdx.x] = 0u; }
  const int wave = threadIdx.x >> 6, lane = threadIdx.x & 63;
  const int rw = wave >> 1, cw = wave & 1;
  const int rbase = blockIdx.x * 128;
  // DMA source: lane i -> row wave*32 + (i&31), k-half (i>>5) (16B each)
  const char* gsrc = (const char*)(A + (size_t)(rbase + wave * 32 + (lane & 31)) * K)
                   + (lane >> 5) * 16;
  char* lb[2] = { &Atile[0][wave * 1024], &Atile[1][wave * 1024] };

  {  // stage BK 0: 4 microtiles per wave (one per k-step)
#pragma unroll
    for (int s = 0; s < 4; ++s) load_lds16(gsrc + s * 32, lb[0] + s * 4096);
  }

  const __hip_bfloat16* wbase = Wpk + ((size_t)(cw * 4) * S * 64 + lane) * 8;
  f32x16 acc[2][4] = {};

  for (int kb = 0; kb < NIT; ++kb) {
    __syncthreads();  // drains DMAs for buf[kb&1]; other buf free for prefetch
    if (kb + 1 < NIT) {
      const char* g = gsrc + (size_t)(kb + 1) * 128;
      char* l = lb[(kb + 1) & 1];
#pragma unroll
      for (int s = 0; s < 4; ++s) load_lds16(g + s * 32, l + s * 4096);
    }
    const char* ab = Atile[kb & 1];
#pragma unroll
    for (int s = 0; s < 4; ++s) {
      const int ks = kb * 4 + s;
      const bf16x8 a0 = *(const bf16x8*)(ab + (s * 4 + rw * 2 + 0) * 1024 + lane * 16);
      const bf16x8 a1 = *(const bf16x8*)(ab + (s * 4 + rw * 2 + 1) * 1024 + lane * 16);
      const bf16x8 w0 = *(const bf16x8*)(wbase + ((size_t)0 * S + ks) * 512);
      const bf16x8 w1 = *(const bf16x8*)(wbase + ((size_t)1 * S + ks) * 512);
      const bf16x8 w2 = *(const bf16x8*)(wbase + ((size_t)2 * S + ks) * 512);
      const bf16x8 w3 = *(const bf16x8*)(wbase + ((size_t)3 * S + ks) * 512);
      acc[0][0] = __builtin_amdgcn_mfma_f32_32x32x16_bf16(a0, w0, acc[0][0], 0, 0, 0);
      acc[0][1] = __builtin_amdgcn_mfma_f32_32x32x16_bf16(a0, w1, acc[0][1], 0, 0, 0);
      acc[0][2] = __builtin_amdgcn_mfma_f32_32x32x16_bf16(a0, w2, acc[0][2], 0, 0, 0);
      acc[0][3] = __builtin_amdgcn_mfma_f32_32x32x16_bf16(a0, w3, acc[0][3], 0, 0, 0);
      acc[1][0] = __builtin_amdgcn_mfma_f32_32x32x16_bf16(a1, w0, acc[1][0], 0, 0, 0);
      acc[1][1] = __builtin_amdgcn_mfma_f32_32x32x16_bf16(a1, w1, acc[1][1], 0, 0, 0);
      acc[1][2] = __builtin_amdgcn_mfma_f32_32x32x16_bf16(a1, w2, acc[1][2], 0, 0, 0);
      acc[1][3] = __builtin_amdgcn_mfma_f32_32x32x16_bf16(a1, w3, acc[1][3], 0, 0, 0);
    }
  }

#pragma unroll
  for (int rh = 0; rh < 2; ++rh) {
#pragma unroll
    for (int t = 0; t < 4; ++t) {
      const int col = cw * 128 + t * 32 + (lane & 31);
      const float bj = bias[col];
      float ls = 0.f, ls2 = 0.f, lmax = -INFINITY, lmin = INFINITY;
#pragma unroll
      for (int r = 0; r < 16; ++r) {
        const int row = rbase + rw * 64 + rh * 32 + (r & 3) + 8 * (r >> 2) + 4 * (lane >> 5);
        if (row < M) {
          float v = acc[rh][t][r] + bj;
          if (STORE) Cb[(size_t)row * 768 + 512 + col] = __float2bfloat16(v);
          ls += v;
          ls2 = fmaf(v, v, ls2);
          if (!STORE) { lmax = fmaxf(lmax, v); lmin = fminf(lmin, v); }
        }
      }
      atomicAdd(&colsum[col], ls);
      atomicAdd(&colsum2[col], ls2);
      if (!STORE) {
        atomicMax(&cmax[col], fkey(lmax));
        atomicMax(&cmin[col], ~fkey(lmin));
      }
    }
  }
  __syncthreads();
  atomicAdd(&bnsum[threadIdx.x], colsum[threadIdx.x]);
  atomicAdd(&bnsum2[threadIdx.x], colsum2[threadIdx.x]);
  if (!STORE) {
    atomicMax(&gmax[threadIdx.x], cmax[threadIdx.x]);
    atomicMax(&gmin[threadIdx.x], cmin[threadIdx.x]);
    __threadfence();
    if (threadIdx.x == 0) {
      lastflag = (atomicAdd(counter, 1) == (int)gridDim.x - 1);
      votes = 0;
    }
    __syncthreads();
    if (lastflag) {
      unsigned e = (xw[threadIdx.x] >> 7) & 0xFFu;
      if (e >= 100u && e <= 140u) atomicAdd(&votes, 1);
      __syncthreads();
      const int bf = votes > 128;
      const int j = threadIdx.x;
      if (j < out_size) {
        float sv = atomicAdd(&bnsum[j], 0.f);
        float s2 = atomicAdd(&bnsum2[j], 0.f);
        unsigned km = atomicAdd(&gmax[j], 0u);
        unsigned kn = atomicAdd(&gmin[j], 0u);
        float mu = sv * inv_n;
        float rs = rsqrtf(fmaxf(s2 * inv_n - mu * mu, 0.f) + BN_EPS);
        float g = gamma[j] * rs, b = fmaf(-mu, g, beta[j]);
        float vmax = finv(km), vmin = finv(~kn);
        float v = fmaxf(fmaf(g, (g >= 0.f) ? vmax : vmin, b), 0.f);
        if (bf) ((__hip_bfloat16*)out)[j] = __float2bfloat16(v);
        else    ((float*)out)[j] = v;
      }
    }
  }
}

// ---------- BN+ReLU in place on A2 self-slice (4 cols/thread, 4 rows/block) ----------
__global__ void bn_apply_kernel(__hip_bfloat16* __restrict__ A2,
                                const float* __restrict__ sum, const float* __restrict__ sumsq,
                                const float* __restrict__ gamma, const float* __restrict__ beta,
                                int n_nodes, float inv_n) {
  const int j0 = (threadIdx.x & 63) * 4;
  const int row = blockIdx.x * 4 + (threadIdx.x >> 6);
  if (row >= n_nodes) return;
  float g[4], b[4];
#pragma unroll
  for (int k = 0; k < 4; ++k) {
    const int j = j0 + k;
    float mu = sum[j] * inv_n;
    float rs = rsqrtf(fmaxf(sumsq[j] * inv_n - mu * mu, 0.f) + BN_EPS);
    g[k] = gamma[j] * rs;
    b[k] = fmaf(-mu, g[k], beta[j]);
  }
  uint2* p = (uint2*)(A2 + (size_t)row * 768 + 512 + j0);
  uint2 w = *p;
  unsigned short us[4];
  us[0] = f2bf(fmaxf(fmaf(blo(w.x), g[0], b[0]), 0.f));
  us[1] = f2bf(fmaxf(fmaf(bhi(w.x), g[1], b[1]), 0.f));
  us[2] = f2bf(fmaxf(fmaf(blo(w.y), g[2], b[2]), 0.f));
  us[3] = f2bf(fmaxf(fmaf(bhi(w.y), g[3], b[3]), 0.f));
  *p = *(uint2*)us;
}

extern "C" void kernel_launch(void* const* d_in, const int* in_sizes, int n_in,
                              void* d_out, int out_size, void* d_ws, size_t ws_size,
                              hipStream_t stream) {
  const void* x  = d_in[0];
  const void* ei = d_in[1];
  const int n_nodes = in_sizes[0] / IN_DIM;
  const int n_edges = in_sizes[1] / 2;
  const int nb = (n_nodes + 255) / 256;
  const int Mpad = (n_nodes + 127) & ~127;

  float* ws = (float*)d_ws;
  size_t off = 0;
  auto alloc = [&](size_t n) {
    float* p = ws + off;
    off += (n + 1023) & ~(size_t)1023;
    return p;
  };
  __hip_bfloat16* Wpk1 = (__hip_bfloat16*)alloc(384 * 256 / 2);
  __hip_bfloat16* Wpk2 = (__hip_bfloat16*)alloc(768 * 256 / 2);
  float* b1      = alloc(256);
  float* b2      = alloc(256);
  float* gamma1  = alloc(256);
  float* beta1   = alloc(256);
  float* gamma2  = alloc(256);
  float* beta2   = alloc(256);
  float* zeros   = alloc(2 * (size_t)n_nodes + 2048);
  int*   degf    = (int*)zeros;
  int*   degb    = degf + n_nodes;
  float* sum1    = zeros + 2 * (size_t)n_nodes;
  float* sumsq1  = sum1 + 256;
  float* sum2    = sum1 + 512;
  float* sumsq2  = sum1 + 768;
  unsigned* max2 = (unsigned*)(sum1 + 1024);
  unsigned* min2 = (unsigned*)(sum1 + 1280);
  int*   counter = (int*)(sum1 + 1536);
  int*   offf    = (int*)alloc(n_nodes + 1);
  int*   offb    = (int*)alloc(n_nodes + 1);
  int*   curf    = (int*)alloc(n_nodes);
  int*   curb    = (int*)alloc(n_nodes);
  int*   adjf    = (int*)alloc(n_edges);
  int*   adjb    = (int*)alloc(n_edges);
  int*   partials = (int*)alloc(2 * nb);
  __hip_bfloat16* A1 = (__hip_bfloat16*)alloc((size_t)Mpad * 384 / 2);
  __hip_bfloat16* A2 = (__hip_bfloat16*)alloc((size_t)Mpad * 768 / 2);
  (void)ws_size; (void)n_in;

  hipMemsetAsync(zeros, 0, (2 * (size_t)n_nodes + 2048) * 4, stream);

  const int pgrid = (n_edges + 255) / 256;
  prep_kernel<<<pgrid, 256, 0, stream>>>(
      x, ei,
      d_in[2], d_in[3], d_in[4], d_in[5], d_in[6], d_in[7],
      d_in[8], d_in[9], d_in[10], d_in[11], d_in[12], d_in[13],
      d_in[14], d_in[15], d_in[16], d_in[17],
      degf, degb, A1,
      Wpk1, b1, Wpk2, b2, gamma1, beta1, gamma2, beta2, n_nodes, n_edges);

  scan_part_kernel<<<2 * nb, 256, 0, stream>>>(degf, degb, offf, offb, partials, n_nodes, nb);
  scan_add_kernel<<<2 * nb, 256, 0, stream>>>(offf, offb, curf, curb, partials, n_nodes, nb, n_edges);
  fill_adj_kernel<<<(n_edges + 255) / 256, 256, 0, stream>>>(ei, curf, curb, adjf, adjb, n_edges);

  const float inv_n = 1.0f / (float)n_nodes;
  const int gemm_grid = Mpad / 128;

  // ---- layer 1 ----
  gather_mean_kernel<IN_DIM><<<(2 * n_nodes + 3) / 4, 256, 0, stream>>>(
      A1, adjf, offf, adjb, offb, n_nodes);
  gemm_mfma_kernel<384, true><<<gemm_grid, 256, 0, stream>>>(
      A1, Wpk1, b1, A2, sum1, sumsq1, max2, min2, counter, (const unsigned*)x,
      gamma1, beta1, inv_n, d_out, out_size, n_nodes);
  bn_apply_kernel<<<(n_nodes + 3) / 4, 256, 0, stream>>>(
      A2, sum1, sumsq1, gamma1, beta1, n_nodes, inv_n);

  // ---- layer 2 (no C store; stats+max/min fused; last block writes output) ----
  gather_mean_kernel<HID><<<(2 * n_nodes + 3) / 4, 256, 0, stream>>>(
      A2, adjf, offf, adjb, offb, n_nodes);
  gemm_mfma_kernel<768, false><<<gemm_grid, 256, 0, stream>>>(
      A2, Wpk2, b2, nullptr, sum2, sumsq2, max2, min2, counter, (const unsigned*)x,
      gamma2, beta2, inv_n, d_out, out_size, n_nodes);
}

// Round 12
// 377.167 us; speedup vs baseline: 1.0891x; 1.0477x over previous
//
#include <hip/hip_runtime.h>
#include <hip/hip_bf16.h>

#define IN_DIM 128
#define HID 256
#define BN_EPS 1e-5f

typedef __attribute__((ext_vector_type(8))) short bf16x8;
typedef __attribute__((ext_vector_type(16))) float f32x16;

// ---------- helpers ----------
__device__ __forceinline__ float ld_f(const void* p, size_t i, int bf16) {
  if (bf16) return __bfloat162float(((const __hip_bfloat16*)p)[i]);
  return ((const float*)p)[i];
}
__device__ __forceinline__ float blo(unsigned u) { return __uint_as_float(u << 16); }
__device__ __forceinline__ float bhi(unsigned u) { return __uint_as_float(u & 0xffff0000u); }
__device__ __forceinline__ unsigned short f2bf(float f) {
  __hip_bfloat16 b = __float2bfloat16(f);
  return __builtin_bit_cast(unsigned short, b);
}
__device__ __forceinline__ void load_lds16(const void* g, void* l) {
  __builtin_amdgcn_global_load_lds((const __attribute__((address_space(1))) void*)g,
                                   (__attribute__((address_space(3))) void*)l, 16, 0, 0);
}
// order-preserving float->uint key (monotone increasing); init 0 is neutral for max
__device__ __forceinline__ unsigned fkey(float v) {
  unsigned s = __float_as_uint(v);
  return (s & 0x80000000u) ? ~s : (s | 0x80000000u);
}
__device__ __forceinline__ float finv(unsigned k) {
  unsigned s = (k & 0x80000000u) ? (k ^ 0x80000000u) : ~k;
  return __uint_as_float(s);
}

// ---------- mega prep: flag detect (per block) + histogram + x->A1 + W packs ----------
__global__ void prep_kernel(
    const void* __restrict__ x, const void* __restrict__ ei,
    const void* Wl_f1, const void* bl_f1, const void* Wr_f1,
    const void* Wl_b1, const void* bl_b1, const void* Wr_b1,
    const void* Wl_f2, const void* bl_f2, const void* Wr_f2,
    const void* Wl_b2, const void* bl_b2, const void* Wr_b2,
    const void* g1, const void* be1, const void* g2, const void* be2,
    int* __restrict__ degf, int* __restrict__ degb,
    __hip_bfloat16* __restrict__ A1,
    __hip_bfloat16* __restrict__ Wpk1, float* __restrict__ b1,
    __hip_bfloat16* __restrict__ Wpk2, float* __restrict__ b2,
    float* __restrict__ gamma1, float* __restrict__ beta1,
    float* __restrict__ gamma2, float* __restrict__ beta2,
    int n_nodes, int n_edges) {
  __shared__ int votes, nz;
  if (threadIdx.x == 0) { votes = 0; nz = 0; }
  __syncthreads();
  {
    unsigned e = (((const unsigned*)x)[threadIdx.x] >> 7) & 0xFFu;
    if (e >= 100u && e <= 140u) atomicAdd(&votes, 1);
    if (((const unsigned*)ei)[2 * threadIdx.x + 1] != 0u) atomicAdd(&nz, 1);
  }
  __syncthreads();
  const int bf = (votes > 128) ? 1 : 0;
  const int i32 = (nz > 0) ? 1 : 0;
  const int tid = blockIdx.x * 256 + threadIdx.x;
  const int nt = gridDim.x * 256;
  for (int i = tid; i < n_edges; i += nt) {
    int s, d;
    if (i32) { s = ((const int*)ei)[i]; d = ((const int*)ei)[n_edges + i]; }
    else     { s = (int)((const long long*)ei)[i]; d = (int)((const long long*)ei)[n_edges + i]; }
    atomicAdd(&degf[d], 1);
    atomicAdd(&degb[s], 1);
  }
  const size_t nq = (size_t)n_nodes * IN_DIM / 4;
  for (size_t q = tid; q < nq; q += nt) {
    const int row = (int)(q >> 5), j = (int)(q & 31) * 4;
    __hip_bfloat16* dstp = A1 + (size_t)row * 384 + 256 + j;
    if (bf) {
      *(uint2*)dstp = ((const uint2*)x)[q];
    } else {
      float4 v = ((const float4*)x)[q];
      unsigned short o[4] = {f2bf(v.x), f2bf(v.y), f2bf(v.z), f2bf(v.w)};
      *(uint2*)dstp = *(uint2*)o;
    }
  }
  for (int idx = tid; idx < 768 * 256; idx += nt) {
    {
      int j = idx & 7, l = (idx >> 3) & 63, rest = idx >> 9;
      int s = rest % 48, t = rest / 48;
      int k = s * 16 + (l >> 5) * 8 + j, col = t * 32 + (l & 31);
      float v;
      if (k < 256)      v = ld_f(Wl_f2, (size_t)k * 256 + col, bf);
      else if (k < 512) v = ld_f(Wl_b2, (size_t)(k - 256) * 256 + col, bf);
      else              v = ld_f(Wr_f2, (size_t)(k - 512) * 256 + col, bf) +
                            ld_f(Wr_b2, (size_t)(k - 512) * 256 + col, bf);
      Wpk2[idx] = __float2bfloat16(v);
    }
    if (idx < 384 * 256) {
      int j = idx & 7, l = (idx >> 3) & 63, rest = idx >> 9;
      int s = rest % 24, t = rest / 24;
      int k = s * 16 + (l >> 5) * 8 + j, col = t * 32 + (l & 31);
      float v;
      if (k < 128)      v = ld_f(Wl_f1, (size_t)k * 256 + col, bf);
      else if (k < 256) v = ld_f(Wl_b1, (size_t)(k - 128) * 256 + col, bf);
      else              v = ld_f(Wr_f1, (size_t)(k - 256) * 256 + col, bf) +
                            ld_f(Wr_b1, (size_t)(k - 256) * 256 + col, bf);
      Wpk1[idx] = __float2bfloat16(v);
    }
    if (idx < 256) {
      b1[idx] = ld_f(bl_f1, idx, bf) + ld_f(bl_b1, idx, bf);
      b2[idx] = ld_f(bl_f2, idx, bf) + ld_f(bl_b2, idx, bf);
      gamma1[idx] = ld_f(g1, idx, bf);
      beta1[idx]  = ld_f(be1, idx, bf);
      gamma2[idx] = ld_f(g2, idx, bf);
      beta2[idx]  = ld_f(be2, idx, bf);
    }
  }
}

// ---------- CSR build ----------
__global__ void scan_part_kernel(const int* __restrict__ degf, const int* __restrict__ degb,
                                 int* __restrict__ offf, int* __restrict__ offb,
                                 int* __restrict__ partials, int n, int nb) {
  __shared__ int buf[256];
  const int b = blockIdx.x;
  const int* deg = (b < nb) ? degf : degb;
  int* off = (b < nb) ? offf : offb;
  const int chunk = (b < nb) ? b : (b - nb);
  const int i = chunk * 256 + threadIdx.x;
  int v = (i < n) ? deg[i] : 0;
  buf[threadIdx.x] = v;
  __syncthreads();
  for (int s = 1; s < 256; s <<= 1) {
    int t = (threadIdx.x >= s) ? buf[threadIdx.x - s] : 0;
    __syncthreads();
    buf[threadIdx.x] += t;
    __syncthreads();
  }
  if (i < n) off[i] = buf[threadIdx.x] - v;
  if (threadIdx.x == 255) partials[b] = buf[255];
}

// merged: each block reduces its own prefix over partials (nb <= 256) then adds
__global__ void scan_add_kernel(int* __restrict__ offf, int* __restrict__ offb,
                                int* __restrict__ curf, int* __restrict__ curb,
                                const int* __restrict__ partials, int n, int nb, int n_edges) {
  __shared__ int red[256];
  const int b = blockIdx.x;
  int* off = (b < nb) ? offf : offb;
  int* cur = (b < nb) ? curf : curb;
  const int chunk = (b < nb) ? b : (b - nb);
  const int abase = (b < nb) ? 0 : nb;
  int v = (threadIdx.x < chunk) ? partials[abase + threadIdx.x] : 0;
  red[threadIdx.x] = v;
  __syncthreads();
  for (int s = 128; s > 0; s >>= 1) {
    if (threadIdx.x < s) red[threadIdx.x] += red[threadIdx.x + s];
    __syncthreads();
  }
  const int prefix = red[0];
  const int i = chunk * 256 + threadIdx.x;
  if (i < n) {
    int t = off[i] + prefix;
    off[i] = t;
    cur[i] = t;
  }
  if (b == 0 && threadIdx.x == 0) { offf[n] = n_edges; offb[n] = n_edges; }
}

// decodes edge_index directly (per-block int64 vote)
__global__ void fill_adj_kernel(const void* __restrict__ ei,
                                int* __restrict__ curf, int* __restrict__ curb,
                                int* __restrict__ adjf, int* __restrict__ adjb, int n_edges) {
  __shared__ int nz;
  if (threadIdx.x == 0) nz = 0;
  __syncthreads();
  if (((const unsigned*)ei)[2 * threadIdx.x + 1] != 0u) atomicAdd(&nz, 1);
  __syncthreads();
  const int i32 = nz > 0;
  int i = blockIdx.x * 256 + threadIdx.x;
  if (i >= n_edges) return;
  int s, d;
  if (i32) { s = ((const int*)ei)[i]; d = ((const int*)ei)[n_edges + i]; }
  else     { s = (int)((const long long*)ei)[i]; d = (int)((const long long*)ei)[n_edges + i]; }
  adjf[atomicAdd(&curf[d], 1)] = s;
  adjb[atomicAdd(&curb[s], 1)] = d;
}

// ---------- gather-mean v3 (benched 58.6us): unroll x2, 4 rows + 2 idx in flight ----------
template <int D>
__global__ __launch_bounds__(256) void gather_mean_kernel(
    __hip_bfloat16* __restrict__ A,
    const int* __restrict__ adjf, const int* __restrict__ offf,
    const int* __restrict__ adjb, const int* __restrict__ offb, int n_nodes) {
  constexpr int LPN = D / 8;
  constexpr int NPI = 64 / LPN;
  const int gw = (int)(((size_t)blockIdx.x * 256 + threadIdx.x) >> 6);
  const int lane = threadIdx.x & 63;
  if (gw >= 2 * n_nodes) return;
  int node, dir;
  const int *adj, *off;
  if (gw < n_nodes) { node = gw;           adj = adjf; off = offf; dir = 0; }
  else              { node = gw - n_nodes; adj = adjb; off = offb; dir = 1; }
  const int s = off[node], e = off[node + 1];
  const int sub = lane / LPN, cl = lane % LPN;
  const size_t coloff = 2 * (size_t)D + cl * 8;
  auto clampi = [&](int i) { return max(min(i, e - 1), 0); };
  auto ROW = [&](int a) { return *(const uint4*)(A + (size_t)a * (3 * D) + coloff); };
  float acc[8] = {0.f, 0.f, 0.f, 0.f, 0.f, 0.f, 0.f, 0.f};
  int i = s + sub;
  int a0 = adj[clampi(i)];
  int a1 = adj[clampi(i + NPI)];
  int a2 = adj[clampi(i + 2 * NPI)];
  int a3 = adj[clampi(i + 3 * NPI)];
  uint4 r0 = ROW(a0);
  uint4 r1 = ROW(a1);
  for (; i < e; i += 2 * NPI) {
    const uint4 r2 = ROW(a2), r3 = ROW(a3);  // next pair in flight
    const int a4 = adj[clampi(i + 4 * NPI)];
    const int a5 = adj[clampi(i + 5 * NPI)];
    acc[0] += blo(r0.x); acc[1] += bhi(r0.x);
    acc[2] += blo(r0.y); acc[3] += bhi(r0.y);
    acc[4] += blo(r0.z); acc[5] += bhi(r0.z);
    acc[6] += blo(r0.w); acc[7] += bhi(r0.w);
    if (i + NPI < e) {
      acc[0] += blo(r1.x); acc[1] += bhi(r1.x);
      acc[2] += blo(r1.y); acc[3] += bhi(r1.y);
      acc[4] += blo(r1.z); acc[5] += bhi(r1.z);
      acc[6] += blo(r1.w); acc[7] += bhi(r1.w);
    }
    r0 = r2; r1 = r3; a2 = a4; a3 = a5;
  }
#pragma unroll
  for (int o = 32; o >= LPN; o >>= 1) {
#pragma unroll
    for (int k = 0; k < 8; ++k) acc[k] += __shfl_xor(acc[k], o, 64);
  }
  if (sub == 0) {
    const float inv = 1.0f / (float)max(e - s, 1);
    union { unsigned short us[8]; uint4 v; } o;
#pragma unroll
    for (int k = 0; k < 8; ++k) o.us[k] = f2bf(acc[k] * inv);
    *(uint4*)(A + (size_t)node * (3 * D) + dir * D + cl * 8) = o.v;
  }
}

// ---------- MFMA GEMM v8: v6 structure (BK=128, 6 barriers) + conflict-free LDS ----------
// block = 128r x 256c, 4 waves each 64r x 128c (8 C-frags / 128 AGPRs).
// DMA: lane i stages row (i&31), k-half (i>>5); 8 DMAs/wave/iter (one per k-step d).
// Microtile (d 0..7, rowgrp g 0..3) at LDS offset (d*4+g)*1024; reader addr = lane*16
// (wave-contiguous 1KB, zero bank conflicts — verified r11).
// STORE=true (layer 1): bf16 pre-BN -> Cb (stride 768, off 512); sums only.
// STORE=false (layer 2): no C store; sums + order-key max/min (finalize is separate).
template <int K, bool STORE>
__global__ __launch_bounds__(256, 2) void gemm_mfma_kernel(
    const __hip_bfloat16* __restrict__ A, const __hip_bfloat16* __restrict__ Wpk,
    const float* __restrict__ bias, __hip_bfloat16* __restrict__ Cb,
    float* __restrict__ bnsum, float* __restrict__ bnsum2,
    unsigned* __restrict__ gmax, unsigned* __restrict__ gmin, int M) {
  constexpr int S = K / 16;    // total k-steps
  constexpr int NIT = K / 128; // BK=128 iterations
  __shared__ __align__(16) char Atile[2][32768];
  __shared__ float colsum[256], colsum2[256];
  __shared__ unsigned cmax[256], cmin[256];
  colsum[threadIdx.x] = 0.f; colsum2[threadIdx.x] = 0.f;
  if (!STORE) { cmax[threadIdx.x] = 0u; cmin[threadIdx.x] = 0u; }
  const int wave = threadIdx.x >> 6, lane = threadIdx.x & 63;
  const int rw = wave >> 1, cw = wave & 1;
  const int rbase = blockIdx.x * 128;
  // DMA source: lane i -> row (i&31) of row-group `wave`, k-half (i>>5)
  const char* gsrc = (const char*)(A + (size_t)(rbase + wave * 32 + (lane & 31)) * K)
                   + (lane >> 5) * 16;
  char* lb[2] = { &Atile[0][wave * 1024], &Atile[1][wave * 1024] };

  {  // stage iter 0: 8 microtiles (k-steps) for this wave's row-group
#pragma unroll
    for (int d = 0; d < 8; ++d) load_lds16(gsrc + d * 32, lb[0] + d * 4096);
  }

  const __hip_bfloat16* wbase = Wpk + ((size_t)(cw * 4) * S * 64 + lane) * 8;
  f32x16 acc[2][4] = {};

  for (int kb = 0; kb < NIT; ++kb) {
    __syncthreads();  // drains DMAs for buf[kb&1]
    if (kb + 1 < NIT) {
      const char* g = gsrc + (size_t)(kb + 1) * 256;
      char* l = lb[(kb + 1) & 1];
#pragma unroll
      for (int d = 0; d < 8; ++d) load_lds16(g + d * 32, l + d * 4096);
    }
    const char* ab = Atile[kb & 1];
#pragma unroll
    for (int s = 0; s < 8; ++s) {
      const int ks = kb * 8 + s;
      const bf16x8 a0 = *(const bf16x8*)(ab + (s * 4 + rw * 2 + 0) * 1024 + lane * 16);
      const bf16x8 a1 = *(const bf16x8*)(ab + (s * 4 + rw * 2 + 1) * 1024 + lane * 16);
      const bf16x8 w0 = *(const bf16x8*)(wbase + ((size_t)0 * S + ks) * 512);
      const bf16x8 w1 = *(const bf16x8*)(wbase + ((size_t)1 * S + ks) * 512);
      const bf16x8 w2 = *(const bf16x8*)(wbase + ((size_t)2 * S + ks) * 512);
      const bf16x8 w3 = *(const bf16x8*)(wbase + ((size_t)3 * S + ks) * 512);
      acc[0][0] = __builtin_amdgcn_mfma_f32_32x32x16_bf16(a0, w0, acc[0][0], 0, 0, 0);
      acc[0][1] = __builtin_amdgcn_mfma_f32_32x32x16_bf16(a0, w1, acc[0][1], 0, 0, 0);
      acc[0][2] = __builtin_amdgcn_mfma_f32_32x32x16_bf16(a0, w2, acc[0][2], 0, 0, 0);
      acc[0][3] = __builtin_amdgcn_mfma_f32_32x32x16_bf16(a0, w3, acc[0][3], 0, 0, 0);
      acc[1][0] = __builtin_amdgcn_mfma_f32_32x32x16_bf16(a1, w0, acc[1][0], 0, 0, 0);
      acc[1][1] = __builtin_amdgcn_mfma_f32_32x32x16_bf16(a1, w1, acc[1][1], 0, 0, 0);
      acc[1][2] = __builtin_amdgcn_mfma_f32_32x32x16_bf16(a1, w2, acc[1][2], 0, 0, 0);
      acc[1][3] = __builtin_amdgcn_mfma_f32_32x32x16_bf16(a1, w3, acc[1][3], 0, 0, 0);
    }
  }

#pragma unroll
  for (int rh = 0; rh < 2; ++rh) {
#pragma unroll
    for (int t = 0; t < 4; ++t) {
      const int col = cw * 128 + t * 32 + (lane & 31);
      const float bj = bias[col];
      float ls = 0.f, ls2 = 0.f, lmax = -INFINITY, lmin = INFINITY;
#pragma unroll
      for (int r = 0; r < 16; ++r) {
        const int row = rbase + rw * 64 + rh * 32 + (r & 3) + 8 * (r >> 2) + 4 * (lane >> 5);
        if (row < M) {
          float v = acc[rh][t][r] + bj;
          if (STORE) Cb[(size_t)row * 768 + 512 + col] = __float2bfloat16(v);
          ls += v;
          ls2 = fmaf(v, v, ls2);
          if (!STORE) { lmax = fmaxf(lmax, v); lmin = fminf(lmin, v); }
        }
      }
      atomicAdd(&colsum[col], ls);
      atomicAdd(&colsum2[col], ls2);
      if (!STORE) {
        atomicMax(&cmax[col], fkey(lmax));
        atomicMax(&cmin[col], ~fkey(lmin));
      }
    }
  }
  __syncthreads();
  atomicAdd(&bnsum[threadIdx.x], colsum[threadIdx.x]);
  atomicAdd(&bnsum2[threadIdx.x], colsum2[threadIdx.x]);
  if (!STORE) {
    atomicMax(&gmax[threadIdx.x], cmax[threadIdx.x]);
    atomicMax(&gmin[threadIdx.x], cmin[threadIdx.x]);
  }
}

// ---------- BN+ReLU in place on A2 self-slice (4 cols/thread, 4 rows/block) ----------
__global__ void bn_apply_kernel(__hip_bfloat16* __restrict__ A2,
                                const float* __restrict__ sum, const float* __restrict__ sumsq,
                                const float* __restrict__ gamma, const float* __restrict__ beta,
                                int n_nodes, float inv_n) {
  const int j0 = (threadIdx.x & 63) * 4;
  const int row = blockIdx.x * 4 + (threadIdx.x >> 6);
  if (row >= n_nodes) return;
  float g[4], b[4];
#pragma unroll
  for (int k = 0; k < 4; ++k) {
    const int j = j0 + k;
    float mu = sum[j] * inv_n;
    float rs = rsqrtf(fmaxf(sumsq[j] * inv_n - mu * mu, 0.f) + BN_EPS);
    g[k] = gamma[j] * rs;
    b[k] = fmaf(-mu, g[k], beta[j]);
  }
  uint2* p = (uint2*)(A2 + (size_t)row * 768 + 512 + j0);
  uint2 w = *p;
  unsigned short us[4];
  us[0] = f2bf(fmaxf(fmaf(blo(w.x), g[0], b[0]), 0.f));
  us[1] = f2bf(fmaxf(fmaf(bhi(w.x), g[1], b[1]), 0.f));
  us[2] = f2bf(fmaxf(fmaf(blo(w.y), g[2], b[2]), 0.f));
  us[3] = f2bf(fmaxf(fmaf(bhi(w.y), g[3], b[3]), 0.f));
  *p = *(uint2*)us;
}

// ---------- finalize: out[j] from fused layer-2 stats (monotone max/min trick) ----------
__global__ void finalize_kernel(const unsigned* __restrict__ xw,
                                const float* __restrict__ sum, const float* __restrict__ sumsq,
                                const unsigned* __restrict__ gmax, const unsigned* __restrict__ gmin,
                                const float* __restrict__ gamma, const float* __restrict__ beta,
                                float inv_n, void* __restrict__ out, int out_size) {
  __shared__ int votes;
  if (threadIdx.x == 0) votes = 0;
  __syncthreads();
  unsigned e = (xw[threadIdx.x] >> 7) & 0xFFu;
  if (e >= 100u && e <= 140u) atomicAdd(&votes, 1);
  __syncthreads();
  int bf = votes > 128;
  int j = threadIdx.x;
  if (j >= out_size) return;
  float mu = sum[j] * inv_n;
  float rs = rsqrtf(fmaxf(sumsq[j] * inv_n - mu * mu, 0.f) + BN_EPS);
  float g = gamma[j] * rs, b = fmaf(-mu, g, beta[j]);
  float vmax = finv(gmax[j]);
  float vmin = finv(~gmin[j]);
  float v = fmaxf(fmaf(g, (g >= 0.f) ? vmax : vmin, b), 0.f);
  if (bf) ((__hip_bfloat16*)out)[j] = __float2bfloat16(v);
  else    ((float*)out)[j] = v;
}

extern "C" void kernel_launch(void* const* d_in, const int* in_sizes, int n_in,
                              void* d_out, int out_size, void* d_ws, size_t ws_size,
                              hipStream_t stream) {
  const void* x  = d_in[0];
  const void* ei = d_in[1];
  const int n_nodes = in_sizes[0] / IN_DIM;
  const int n_edges = in_sizes[1] / 2;
  const int nb = (n_nodes + 255) / 256;
  const int Mpad = (n_nodes + 127) & ~127;

  float* ws = (float*)d_ws;
  size_t off = 0;
  auto alloc = [&](size_t n) {
    float* p = ws + off;
    off += (n + 1023) & ~(size_t)1023;
    return p;
  };
  __hip_bfloat16* Wpk1 = (__hip_bfloat16*)alloc(384 * 256 / 2);
  __hip_bfloat16* Wpk2 = (__hip_bfloat16*)alloc(768 * 256 / 2);
  float* b1      = alloc(256);
  float* b2      = alloc(256);
  float* gamma1  = alloc(256);
  float* beta1   = alloc(256);
  float* gamma2  = alloc(256);
  float* beta2   = alloc(256);
  float* zeros   = alloc(2 * (size_t)n_nodes + 2048);
  int*   degf    = (int*)zeros;
  int*   degb    = degf + n_nodes;
  float* sum1    = zeros + 2 * (size_t)n_nodes;
  float* sumsq1  = sum1 + 256;
  float* sum2    = sum1 + 512;
  float* sumsq2  = sum1 + 768;
  unsigned* max2 = (unsigned*)(sum1 + 1024);
  unsigned* min2 = (unsigned*)(sum1 + 1280);
  int*   offf    = (int*)alloc(n_nodes + 1);
  int*   offb    = (int*)alloc(n_nodes + 1);
  int*   curf    = (int*)alloc(n_nodes);
  int*   curb    = (int*)alloc(n_nodes);
  int*   adjf    = (int*)alloc(n_edges);
  int*   adjb    = (int*)alloc(n_edges);
  int*   partials = (int*)alloc(2 * nb);
  __hip_bfloat16* A1 = (__hip_bfloat16*)alloc((size_t)Mpad * 384 / 2);
  __hip_bfloat16* A2 = (__hip_bfloat16*)alloc((size_t)Mpad * 768 / 2);
  (void)ws_size; (void)n_in;

  hipMemsetAsync(zeros, 0, (2 * (size_t)n_nodes + 2048) * 4, stream);

  const int pgrid = (n_edges + 255) / 256;
  prep_kernel<<<pgrid, 256, 0, stream>>>(
      x, ei,
      d_in[2], d_in[3], d_in[4], d_in[5], d_in[6], d_in[7],
      d_in[8], d_in[9], d_in[10], d_in[11], d_in[12], d_in[13],
      d_in[14], d_in[15], d_in[16], d_in[17],
      degf, degb, A1,
      Wpk1, b1, Wpk2, b2, gamma1, beta1, gamma2, beta2, n_nodes, n_edges);

  scan_part_kernel<<<2 * nb, 256, 0, stream>>>(degf, degb, offf, offb, partials, n_nodes, nb);
  scan_add_kernel<<<2 * nb, 256, 0, stream>>>(offf, offb, curf, curb, partials, n_nodes, nb, n_edges);
  fill_adj_kernel<<<(n_edges + 255) / 256, 256, 0, stream>>>(ei, curf, curb, adjf, adjb, n_edges);

  const float inv_n = 1.0f / (float)n_nodes;
  const int gemm_grid = Mpad / 128;

  // ---- layer 1 ----
  gather_mean_kernel<IN_DIM><<<(2 * n_nodes + 3) / 4, 256, 0, stream>>>(
      A1, adjf, offf, adjb, offb, n_nodes);
  gemm_mfma_kernel<384, true><<<gemm_grid, 256, 0, stream>>>(
      A1, Wpk1, b1, A2, sum1, sumsq1, max2, min2, n_nodes);
  bn_apply_kernel<<<(n_nodes + 3) / 4, 256, 0, stream>>>(
      A2, sum1, sumsq1, gamma1, beta1, n_nodes, inv_n);

  // ---- layer 2 (no C store; stats+max/min fused; separate finalize) ----
  gather_mean_kernel<HID><<<(2 * n_nodes + 3) / 4, 256, 0, stream>>>(
      A2, adjf, offf, adjb, offb, n_nodes);
  gemm_mfma_kernel<768, false><<<gemm_grid, 256, 0, stream>>>(
      A2, Wpk2, b2, nullptr, sum2, sumsq2, max2, min2, n_nodes);
  finalize_kernel<<<1, 256, 0, stream>>>(
      (const unsigned*)x, sum2, sumsq2, max2, min2, gamma2, beta2, inv_n, d_out, out_size);
}

// Round 13
// 374.491 us; speedup vs baseline: 1.0969x; 1.0071x over previous
//
#include <hip/hip_runtime.h>
#include <hip/hip_bf16.h>

#define IN_DIM 128
#define HID 256
#define BN_EPS 1e-5f

typedef __attribute__((ext_vector_type(8))) short bf16x8;
typedef __attribute__((ext_vector_type(16))) float f32x16;

// ---------- helpers ----------
__device__ __forceinline__ float ld_f(const void* p, size_t i, int bf16) {
  if (bf16) return __bfloat162float(((const __hip_bfloat16*)p)[i]);
  return ((const float*)p)[i];
}
__device__ __forceinline__ float blo(unsigned u) { return __uint_as_float(u << 16); }
__device__ __forceinline__ float bhi(unsigned u) { return __uint_as_float(u & 0xffff0000u); }
__device__ __forceinline__ unsigned short f2bf(float f) {
  __hip_bfloat16 b = __float2bfloat16(f);
  return __builtin_bit_cast(unsigned short, b);
}
__device__ __forceinline__ void load_lds16(const void* g, void* l) {
  __builtin_amdgcn_global_load_lds((const __attribute__((address_space(1))) void*)g,
                                   (__attribute__((address_space(3))) void*)l, 16, 0, 0);
}
// order-preserving float->uint key (monotone increasing); init 0 is neutral for max
__device__ __forceinline__ unsigned fkey(float v) {
  unsigned s = __float_as_uint(v);
  return (s & 0x80000000u) ? ~s : (s | 0x80000000u);
}
__device__ __forceinline__ float finv(unsigned k) {
  unsigned s = (k & 0x80000000u) ? (k ^ 0x80000000u) : ~k;
  return __uint_as_float(s);
}

// ---------- mega prep: flag detect (per block) + histogram + x->A1 + W packs ----------
__global__ void prep_kernel(
    const void* __restrict__ x, const void* __restrict__ ei,
    const void* Wl_f1, const void* bl_f1, const void* Wr_f1,
    const void* Wl_b1, const void* bl_b1, const void* Wr_b1,
    const void* Wl_f2, const void* bl_f2, const void* Wr_f2,
    const void* Wl_b2, const void* bl_b2, const void* Wr_b2,
    const void* g1, const void* be1, const void* g2, const void* be2,
    int* __restrict__ degf, int* __restrict__ degb,
    __hip_bfloat16* __restrict__ A1,
    __hip_bfloat16* __restrict__ Wpk1, float* __restrict__ b1,
    __hip_bfloat16* __restrict__ Wpk2, float* __restrict__ b2,
    float* __restrict__ gamma1, float* __restrict__ beta1,
    float* __restrict__ gamma2, float* __restrict__ beta2,
    int n_nodes, int n_edges) {
  __shared__ int votes, nz;
  if (threadIdx.x == 0) { votes = 0; nz = 0; }
  __syncthreads();
  {
    unsigned e = (((const unsigned*)x)[threadIdx.x] >> 7) & 0xFFu;
    if (e >= 100u && e <= 140u) atomicAdd(&votes, 1);
    if (((const unsigned*)ei)[2 * threadIdx.x + 1] != 0u) atomicAdd(&nz, 1);
  }
  __syncthreads();
  const int bf = (votes > 128) ? 1 : 0;
  const int i32 = (nz > 0) ? 1 : 0;
  const int tid = blockIdx.x * 256 + threadIdx.x;
  const int nt = gridDim.x * 256;
  for (int i = tid; i < n_edges; i += nt) {
    int s, d;
    if (i32) { s = ((const int*)ei)[i]; d = ((const int*)ei)[n_edges + i]; }
    else     { s = (int)((const long long*)ei)[i]; d = (int)((const long long*)ei)[n_edges + i]; }
    atomicAdd(&degf[d], 1);
    atomicAdd(&degb[s], 1);
  }
  const size_t nq = (size_t)n_nodes * IN_DIM / 4;
  for (size_t q = tid; q < nq; q += nt) {
    const int row = (int)(q >> 5), j = (int)(q & 31) * 4;
    __hip_bfloat16* dstp = A1 + (size_t)row * 384 + 256 + j;
    if (bf) {
      *(uint2*)dstp = ((const uint2*)x)[q];
    } else {
      float4 v = ((const float4*)x)[q];
      unsigned short o[4] = {f2bf(v.x), f2bf(v.y), f2bf(v.z), f2bf(v.w)};
      *(uint2*)dstp = *(uint2*)o;
    }
  }
  for (int idx = tid; idx < 768 * 256; idx += nt) {
    {
      int j = idx & 7, l = (idx >> 3) & 63, rest = idx >> 9;
      int s = rest % 48, t = rest / 48;
      int k = s * 16 + (l >> 5) * 8 + j, col = t * 32 + (l & 31);
      float v;
      if (k < 256)      v = ld_f(Wl_f2, (size_t)k * 256 + col, bf);
      else if (k < 512) v = ld_f(Wl_b2, (size_t)(k - 256) * 256 + col, bf);
      else              v = ld_f(Wr_f2, (size_t)(k - 512) * 256 + col, bf) +
                            ld_f(Wr_b2, (size_t)(k - 512) * 256 + col, bf);
      Wpk2[idx] = __float2bfloat16(v);
    }
    if (idx < 384 * 256) {
      int j = idx & 7, l = (idx >> 3) & 63, rest = idx >> 9;
      int s = rest % 24, t = rest / 24;
      int k = s * 16 + (l >> 5) * 8 + j, col = t * 32 + (l & 31);
      float v;
      if (k < 128)      v = ld_f(Wl_f1, (size_t)k * 256 + col, bf);
      else if (k < 256) v = ld_f(Wl_b1, (size_t)(k - 128) * 256 + col, bf);
      else              v = ld_f(Wr_f1, (size_t)(k - 256) * 256 + col, bf) +
                            ld_f(Wr_b1, (size_t)(k - 256) * 256 + col, bf);
      Wpk1[idx] = __float2bfloat16(v);
    }
    if (idx < 256) {
      b1[idx] = ld_f(bl_f1, idx, bf) + ld_f(bl_b1, idx, bf);
      b2[idx] = ld_f(bl_f2, idx, bf) + ld_f(bl_b2, idx, bf);
      gamma1[idx] = ld_f(g1, idx, bf);
      beta1[idx]  = ld_f(be1, idx, bf);
      gamma2[idx] = ld_f(g2, idx, bf);
      beta2[idx]  = ld_f(be2, idx, bf);
    }
  }
}

// ---------- CSR build ----------
__global__ void scan_part_kernel(const int* __restrict__ degf, const int* __restrict__ degb,
                                 int* __restrict__ offf, int* __restrict__ offb,
                                 int* __restrict__ partials, int n, int nb) {
  __shared__ int buf[256];
  const int b = blockIdx.x;
  const int* deg = (b < nb) ? degf : degb;
  int* off = (b < nb) ? offf : offb;
  const int chunk = (b < nb) ? b : (b - nb);
  const int i = chunk * 256 + threadIdx.x;
  int v = (i < n) ? deg[i] : 0;
  buf[threadIdx.x] = v;
  __syncthreads();
  for (int s = 1; s < 256; s <<= 1) {
    int t = (threadIdx.x >= s) ? buf[threadIdx.x - s] : 0;
    __syncthreads();
    buf[threadIdx.x] += t;
    __syncthreads();
  }
  if (i < n) off[i] = buf[threadIdx.x] - v;
  if (threadIdx.x == 255) partials[b] = buf[255];
}

// merged: each block reduces its own prefix over partials (nb <= 256) then adds
__global__ void scan_add_kernel(int* __restrict__ offf, int* __restrict__ offb,
                                int* __restrict__ curf, int* __restrict__ curb,
                                const int* __restrict__ partials, int n, int nb, int n_edges) {
  __shared__ int red[256];
  const int b = blockIdx.x;
  int* off = (b < nb) ? offf : offb;
  int* cur = (b < nb) ? curf : curb;
  const int chunk = (b < nb) ? b : (b - nb);
  const int abase = (b < nb) ? 0 : nb;
  int v = (threadIdx.x < chunk) ? partials[abase + threadIdx.x] : 0;
  red[threadIdx.x] = v;
  __syncthreads();
  for (int s = 128; s > 0; s >>= 1) {
    if (threadIdx.x < s) red[threadIdx.x] += red[threadIdx.x + s];
    __syncthreads();
  }
  const int prefix = red[0];
  const int i = chunk * 256 + threadIdx.x;
  if (i < n) {
    int t = off[i] + prefix;
    off[i] = t;
    cur[i] = t;
  }
  if (b == 0 && threadIdx.x == 0) { offf[n] = n_edges; offb[n] = n_edges; }
}

// decodes edge_index directly (per-block int64 vote)
__global__ void fill_adj_kernel(const void* __restrict__ ei,
                                int* __restrict__ curf, int* __restrict__ curb,
                                int* __restrict__ adjf, int* __restrict__ adjb, int n_edges) {
  __shared__ int nz;
  if (threadIdx.x == 0) nz = 0;
  __syncthreads();
  if (((const unsigned*)ei)[2 * threadIdx.x + 1] != 0u) atomicAdd(&nz, 1);
  __syncthreads();
  const int i32 = nz > 0;
  int i = blockIdx.x * 256 + threadIdx.x;
  if (i >= n_edges) return;
  int s, d;
  if (i32) { s = ((const int*)ei)[i]; d = ((const int*)ei)[n_edges + i]; }
  else     { s = (int)((const long long*)ei)[i]; d = (int)((const long long*)ei)[n_edges + i]; }
  adjf[atomicAdd(&curf[d], 1)] = s;
  adjb[atomicAdd(&curb[s], 1)] = d;
}

// ---------- gather-mean (unchanged from r12, measured 58.5us) ----------
template <int D>
__global__ __launch_bounds__(256) void gather_mean_kernel(
    __hip_bfloat16* __restrict__ A,
    const int* __restrict__ adjf, const int* __restrict__ offf,
    const int* __restrict__ adjb, const int* __restrict__ offb, int n_nodes) {
  constexpr int LPN = D / 8;
  constexpr int NPI = 64 / LPN;
  const int gw = (int)(((size_t)blockIdx.x * 256 + threadIdx.x) >> 6);
  const int lane = threadIdx.x & 63;
  if (gw >= 2 * n_nodes) return;
  int node, dir;
  const int *adj, *off;
  if (gw < n_nodes) { node = gw;           adj = adjf; off = offf; dir = 0; }
  else              { node = gw - n_nodes; adj = adjb; off = offb; dir = 1; }
  const int s = off[node], e = off[node + 1];
  const int sub = lane / LPN, cl = lane % LPN;
  const size_t coloff = 2 * (size_t)D + cl * 8;
  auto clampi = [&](int i) { return max(min(i, e - 1), 0); };
  auto ROW = [&](int a) { return *(const uint4*)(A + (size_t)a * (3 * D) + coloff); };
  float acc[8] = {0.f, 0.f, 0.f, 0.f, 0.f, 0.f, 0.f, 0.f};
  int i = s + sub;
  int a0 = adj[clampi(i)];
  int a1 = adj[clampi(i + NPI)];
  int a2 = adj[clampi(i + 2 * NPI)];
  int a3 = adj[clampi(i + 3 * NPI)];
  uint4 r0 = ROW(a0);
  uint4 r1 = ROW(a1);
  for (; i < e; i += 2 * NPI) {
    const uint4 r2 = ROW(a2), r3 = ROW(a3);  // next pair in flight
    const int a4 = adj[clampi(i + 4 * NPI)];
    const int a5 = adj[clampi(i + 5 * NPI)];
    acc[0] += blo(r0.x); acc[1] += bhi(r0.x);
    acc[2] += blo(r0.y); acc[3] += bhi(r0.y);
    acc[4] += blo(r0.z); acc[5] += bhi(r0.z);
    acc[6] += blo(r0.w); acc[7] += bhi(r0.w);
    if (i + NPI < e) {
      acc[0] += blo(r1.x); acc[1] += bhi(r1.x);
      acc[2] += blo(r1.y); acc[3] += bhi(r1.y);
      acc[4] += blo(r1.z); acc[5] += bhi(r1.z);
      acc[6] += blo(r1.w); acc[7] += bhi(r1.w);
    }
    r0 = r2; r1 = r3; a2 = a4; a3 = a5;
  }
#pragma unroll
  for (int o = 32; o >= LPN; o >>= 1) {
#pragma unroll
    for (int k = 0; k < 8; ++k) acc[k] += __shfl_xor(acc[k], o, 64);
  }
  if (sub == 0) {
    const float inv = 1.0f / (float)max(e - s, 1);
    union { unsigned short us[8]; uint4 v; } o;
#pragma unroll
    for (int k = 0; k < 8; ++k) o.us[k] = f2bf(acc[k] * inv);
    *(uint4*)(A + (size_t)node * (3 * D) + dir * D + cl * 8) = o.v;
  }
}

// ---------- MFMA GEMM v9: v8 (BK=128, conflict-free) with stats UNIONed into Atile ----------
// LDS = exactly 65536 B -> two 64KB blocks fit the 160KB pool -> 2 blocks/CU with the
// BK=128 6-barrier cadence (r10 showed 69.6KB forces 1 block/CU). Stats arrays are only
// live after the K-loop, so they alias the A-tile (sequenced by two extra barriers).
template <int K, bool STORE>
__global__ __launch_bounds__(256, 2) void gemm_mfma_kernel(
    const __hip_bfloat16* __restrict__ A, const __hip_bfloat16* __restrict__ Wpk,
    const float* __restrict__ bias, __hip_bfloat16* __restrict__ Cb,
    float* __restrict__ bnsum, float* __restrict__ bnsum2,
    unsigned* __restrict__ gmax, unsigned* __restrict__ gmin, int M) {
  constexpr int S = K / 16;    // total k-steps
  constexpr int NIT = K / 128; // BK=128 iterations
  __shared__ __align__(16) union SMem {
    char at[2][32768];  // A double buffer (K-loop)
    struct { float colsum[256], colsum2[256]; unsigned cmax[256], cmin[256]; } st;  // epilogue
  } sm;
  const int wave = threadIdx.x >> 6, lane = threadIdx.x & 63;
  const int rw = wave >> 1, cw = wave & 1;
  const int rbase = blockIdx.x * 128;
  // DMA source: lane i -> row (i&31) of row-group `wave`, k-half (i>>5)
  const char* gsrc = (const char*)(A + (size_t)(rbase + wave * 32 + (lane & 31)) * K)
                   + (lane >> 5) * 16;
  char* lb[2] = { &sm.at[0][wave * 1024], &sm.at[1][wave * 1024] };

  {  // stage iter 0: 8 microtiles (k-steps) for this wave's row-group
#pragma unroll
    for (int d = 0; d < 8; ++d) load_lds16(gsrc + d * 32, lb[0] + d * 4096);
  }

  const __hip_bfloat16* wbase = Wpk + ((size_t)(cw * 4) * S * 64 + lane) * 8;
  f32x16 acc[2][4] = {};

  for (int kb = 0; kb < NIT; ++kb) {
    __syncthreads();  // drains DMAs for buf[kb&1]
    if (kb + 1 < NIT) {
      const char* g = gsrc + (size_t)(kb + 1) * 256;
      char* l = lb[(kb + 1) & 1];
#pragma unroll
      for (int d = 0; d < 8; ++d) load_lds16(g + d * 32, l + d * 4096);
    }
    const char* ab = sm.at[kb & 1];
#pragma unroll
    for (int s = 0; s < 8; ++s) {
      const int ks = kb * 8 + s;
      const bf16x8 a0 = *(const bf16x8*)(ab + (s * 4 + rw * 2 + 0) * 1024 + lane * 16);
      const bf16x8 a1 = *(const bf16x8*)(ab + (s * 4 + rw * 2 + 1) * 1024 + lane * 16);
      const bf16x8 w0 = *(const bf16x8*)(wbase + ((size_t)0 * S + ks) * 512);
      const bf16x8 w1 = *(const bf16x8*)(wbase + ((size_t)1 * S + ks) * 512);
      const bf16x8 w2 = *(const bf16x8*)(wbase + ((size_t)2 * S + ks) * 512);
      const bf16x8 w3 = *(const bf16x8*)(wbase + ((size_t)3 * S + ks) * 512);
      acc[0][0] = __builtin_amdgcn_mfma_f32_32x32x16_bf16(a0, w0, acc[0][0], 0, 0, 0);
      acc[0][1] = __builtin_amdgcn_mfma_f32_32x32x16_bf16(a0, w1, acc[0][1], 0, 0, 0);
      acc[0][2] = __builtin_amdgcn_mfma_f32_32x32x16_bf16(a0, w2, acc[0][2], 0, 0, 0);
      acc[0][3] = __builtin_amdgcn_mfma_f32_32x32x16_bf16(a0, w3, acc[0][3], 0, 0, 0);
      acc[1][0] = __builtin_amdgcn_mfma_f32_32x32x16_bf16(a1, w0, acc[1][0], 0, 0, 0);
      acc[1][1] = __builtin_amdgcn_mfma_f32_32x32x16_bf16(a1, w1, acc[1][1], 0, 0, 0);
      acc[1][2] = __builtin_amdgcn_mfma_f32_32x32x16_bf16(a1, w2, acc[1][2], 0, 0, 0);
      acc[1][3] = __builtin_amdgcn_mfma_f32_32x32x16_bf16(a1, w3, acc[1][3], 0, 0, 0);
    }
  }

  __syncthreads();  // all waves done reading Atile; safe to alias as stats
  sm.st.colsum[threadIdx.x] = 0.f;
  sm.st.colsum2[threadIdx.x] = 0.f;
  if (!STORE) { sm.st.cmax[threadIdx.x] = 0u; sm.st.cmin[threadIdx.x] = 0u; }
  __syncthreads();

#pragma unroll
  for (int rh = 0; rh < 2; ++rh) {
#pragma unroll
    for (int t = 0; t < 4; ++t) {
      const int col = cw * 128 + t * 32 + (lane & 31);
      const float bj = bias[col];
      float ls = 0.f, ls2 = 0.f, lmax = -INFINITY, lmin = INFINITY;
#pragma unroll
      for (int r = 0; r < 16; ++r) {
        const int row = rbase + rw * 64 + rh * 32 + (r & 3) + 8 * (r >> 2) + 4 * (lane >> 5);
        if (row < M) {
          float v = acc[rh][t][r] + bj;
          if (STORE) Cb[(size_t)row * 768 + 512 + col] = __float2bfloat16(v);
          ls += v;
          ls2 = fmaf(v, v, ls2);
          if (!STORE) { lmax = fmaxf(lmax, v); lmin = fminf(lmin, v); }
        }
      }
      atomicAdd(&sm.st.colsum[col], ls);
      atomicAdd(&sm.st.colsum2[col], ls2);
      if (!STORE) {
        atomicMax(&sm.st.cmax[col], fkey(lmax));
        atomicMax(&sm.st.cmin[col], ~fkey(lmin));
      }
    }
  }
  __syncthreads();
  atomicAdd(&bnsum[threadIdx.x], sm.st.colsum[threadIdx.x]);
  atomicAdd(&bnsum2[threadIdx.x], sm.st.colsum2[threadIdx.x]);
  if (!STORE) {
    atomicMax(&gmax[threadIdx.x], sm.st.cmax[threadIdx.x]);
    atomicMax(&gmin[threadIdx.x], sm.st.cmin[threadIdx.x]);
  }
}

// ---------- BN+ReLU in place on A2 self-slice (4 cols/thread, 4 rows/block) ----------
__global__ void bn_apply_kernel(__hip_bfloat16* __restrict__ A2,
                                const float* __restrict__ sum, const float* __restrict__ sumsq,
                                const float* __restrict__ gamma, const float* __restrict__ beta,
                                int n_nodes, float inv_n) {
  const int j0 = (threadIdx.x & 63) * 4;
  const int row = blockIdx.x * 4 + (threadIdx.x >> 6);
  if (row >= n_nodes) return;
  float g[4], b[4];
#pragma unroll
  for (int k = 0; k < 4; ++k) {
    const int j = j0 + k;
    float mu = sum[j] * inv_n;
    float rs = rsqrtf(fmaxf(sumsq[j] * inv_n - mu * mu, 0.f) + BN_EPS);
    g[k] = gamma[j] * rs;
    b[k] = fmaf(-mu, g[k], beta[j]);
  }
  uint2* p = (uint2*)(A2 + (size_t)row * 768 + 512 + j0);
  uint2 w = *p;
  unsigned short us[4];
  us[0] = f2bf(fmaxf(fmaf(blo(w.x), g[0], b[0]), 0.f));
  us[1] = f2bf(fmaxf(fmaf(bhi(w.x), g[1], b[1]), 0.f));
  us[2] = f2bf(fmaxf(fmaf(blo(w.y), g[2], b[2]), 0.f));
  us[3] = f2bf(fmaxf(fmaf(bhi(w.y), g[3], b[3]), 0.f));
  *p = *(uint2*)us;
}

// ---------- finalize: out[j] from fused layer-2 stats (monotone max/min trick) ----------
__global__ void finalize_kernel(const unsigned* __restrict__ xw,
                                const float* __restrict__ sum, const float* __restrict__ sumsq,
                                const unsigned* __restrict__ gmax, const unsigned* __restrict__ gmin,
                                const float* __restrict__ gamma, const float* __restrict__ beta,
                                float inv_n, void* __restrict__ out, int out_size) {
  __shared__ int votes;
  if (threadIdx.x == 0) votes = 0;
  __syncthreads();
  unsigned e = (xw[threadIdx.x] >> 7) & 0xFFu;
  if (e >= 100u && e <= 140u) atomicAdd(&votes, 1);
  __syncthreads();
  int bf = votes > 128;
  int j = threadIdx.x;
  if (j >= out_size) return;
  float mu = sum[j] * inv_n;
  float rs = rsqrtf(fmaxf(sumsq[j] * inv_n - mu * mu, 0.f) + BN_EPS);
  float g = gamma[j] * rs, b = fmaf(-mu, g, beta[j]);
  float vmax = finv(gmax[j]);
  float vmin = finv(~gmin[j]);
  float v = fmaxf(fmaf(g, (g >= 0.f) ? vmax : vmin, b), 0.f);
  if (bf) ((__hip_bfloat16*)out)[j] = __float2bfloat16(v);
  else    ((float*)out)[j] = v;
}

extern "C" void kernel_launch(void* const* d_in, const int* in_sizes, int n_in,
                              void* d_out, int out_size, void* d_ws, size_t ws_size,
                              hipStream_t stream) {
  const void* x  = d_in[0];
  const void* ei = d_in[1];
  const int n_nodes = in_sizes[0] / IN_DIM;
  const int n_edges = in_sizes[1] / 2;
  const int nb = (n_nodes + 255) / 256;
  const int Mpad = (n_nodes + 127) & ~127;

  float* ws = (float*)d_ws;
  size_t off = 0;
  auto alloc = [&](size_t n) {
    float* p = ws + off;
    off += (n + 1023) & ~(size_t)1023;
    return p;
  };
  __hip_bfloat16* Wpk1 = (__hip_bfloat16*)alloc(384 * 256 / 2);
  __hip_bfloat16* Wpk2 = (__hip_bfloat16*)alloc(768 * 256 / 2);
  float* b1      = alloc(256);
  float* b2      = alloc(256);
  float* gamma1  = alloc(256);
  float* beta1   = alloc(256);
  float* gamma2  = alloc(256);
  float* beta2   = alloc(256);
  float* zeros   = alloc(2 * (size_t)n_nodes + 2048);
  int*   degf    = (int*)zeros;
  int*   degb    = degf + n_nodes;
  float* sum1    = zeros + 2 * (size_t)n_nodes;
  float* sumsq1  = sum1 + 256;
  float* sum2    = sum1 + 512;
  float* sumsq2  = sum1 + 768;
  unsigned* max2 = (unsigned*)(sum1 + 1024);
  unsigned* min2 = (unsigned*)(sum1 + 1280);
  int*   offf    = (int*)alloc(n_nodes + 1);
  int*   offb    = (int*)alloc(n_nodes + 1);
  int*   curf    = (int*)alloc(n_nodes);
  int*   curb    = (int*)alloc(n_nodes);
  int*   adjf    = (int*)alloc(n_edges);
  int*   adjb    = (int*)alloc(n_edges);
  int*   partials = (int*)alloc(2 * nb);
  __hip_bfloat16* A1 = (__hip_bfloat16*)alloc((size_t)Mpad * 384 / 2);
  __hip_bfloat16* A2 = (__hip_bfloat16*)alloc((size_t)Mpad * 768 / 2);
  (void)ws_size; (void)n_in;

  hipMemsetAsync(zeros, 0, (2 * (size_t)n_nodes + 2048) * 4, stream);

  const int pgrid = (n_edges + 255) / 256;
  prep_kernel<<<pgrid, 256, 0, stream>>>(
      x, ei,
      d_in[2], d_in[3], d_in[4], d_in[5], d_in[6], d_in[7],
      d_in[8], d_in[9], d_in[10], d_in[11], d_in[12], d_in[13],
      d_in[14], d_in[15], d_in[16], d_in[17],
      degf, degb, A1,
      Wpk1, b1, Wpk2, b2, gamma1, beta1, gamma2, beta2, n_nodes, n_edges);

  scan_part_kernel<<<2 * nb, 256, 0, stream>>>(degf, degb, offf, offb, partials, n_nodes, nb);
  scan_add_kernel<<<2 * nb, 256, 0, stream>>>(offf, offb, curf, curb, partials, n_nodes, nb, n_edges);
  fill_adj_kernel<<<(n_edges + 255) / 256, 256, 0, stream>>>(ei, curf, curb, adjf, adjb, n_edges);

  const float inv_n = 1.0f / (float)n_nodes;
  const int gemm_grid = Mpad / 128;

  // ---- layer 1 ----
  gather_mean_kernel<IN_DIM><<<(2 * n_nodes + 3) / 4, 256, 0, stream>>>(
      A1, adjf, offf, adjb, offb, n_nodes);
  gemm_mfma_kernel<384, true><<<gemm_grid, 256, 0, stream>>>(
      A1, Wpk1, b1, A2, sum1, sumsq1, max2, min2, n_nodes);
  bn_apply_kernel<<<(n_nodes + 3) / 4, 256, 0, stream>>>(
      A2, sum1, sumsq1, gamma1, beta1, n_nodes, inv_n);

  // ---- layer 2 (no C store; stats+max/min fused; separate finalize) ----
  gather_mean_kernel<HID><<<(2 * n_nodes + 3) / 4, 256, 0, stream>>>(
      A2, adjf, offf, adjb, offb, n_nodes);
  gemm_mfma_kernel<768, false><<<gemm_grid, 256, 0, stream>>>(
      A2, Wpk2, b2, nullptr, sum2, sumsq2, max2, min2, n_nodes);
  finalize_kernel<<<1, 256, 0, stream>>>(
      (const unsigned*)x, sum2, sumsq2, max2, min2, gamma2, beta2, inv_n, d_out, out_size);
}